// Round 1
// baseline (586.360 us; speedup 1.0000x reference)
//
#include <hip/hip_runtime.h>
#include <math.h>

#define NB   8
#define NMEL 80
#define NTXT 512
#define NATT 80
#define NT1  1000
#define NT2  256
#define FTEMP 0.0005f

// ---------------------------------------------------------------------------
// K0: detect mask storage format, compress monotone mask rows to lengths.
// mask row b is [0]*len[b] + [1]*(256-len[b]) (arange >= length).
__global__ void lens_kernel(const void* mask, int* lens) {
    int lane = threadIdx.x;  // 64 threads, 1 wave
    const int* mi = (const int*)mask;
    int bf16p = 0, f16p = 0, f32m = 0, big = 0, one = 0;
    for (int i = lane; i < 512; i += 64) {   // first 2048 bytes: safe in all modes
        unsigned v = (unsigned)mi[i];
        bf16p |= (v == 0x3F803F80u);
        f16p  |= (v == 0x3C003C00u) || (v == 0x3C000000u);
        f32m  |= (v == 0x3F800000u);
        big   |= (v > 1u);
        one   |= (v == 1u);
    }
    bf16p = __any(bf16p); f16p = __any(f16p); f32m = __any(f32m);
    big = __any(big); one = __any(one);
    int mode;
    if (bf16p)      mode = 3;  // bf16 (ushort)
    else if (f16p)  mode = 4;  // f16  (ushort)
    else if (f32m)  mode = 2;  // f32
    else if (big)   mode = 0;  // u8 (numpy bool)  -- most likely
    else if (one)   mode = 1;  // i32
    else            mode = 5;  // all-false
    for (int b = 0; b < NB; ++b) {
        int cnt = 0;
        for (int t = lane; t < NT2; t += 64) {
            bool m;
            switch (mode) {
                case 0: m = ((const unsigned char*)mask)[b*NT2 + t] != 0; break;
                case 1: m = ((const int*)mask)[b*NT2 + t] != 0; break;
                case 2: m = ((const float*)mask)[b*NT2 + t] != 0.f; break;
                case 3: case 4: m = ((const unsigned short*)mask)[b*NT2 + t] != 0; break;
                default: m = false; break;
            }
            cnt += m ? 0 : 1;   // len = count of false (monotone suffix mask)
        }
        for (int off = 32; off > 0; off >>= 1) cnt += __shfl_down(cnt, off);
        if (lane == 0) lens[b] = cnt;
    }
}

// ---------------------------------------------------------------------------
// K1: speaker+emotion channel shifts. One wave per output element.
// First NB*NTXT outputs -> shiftK[b][c] (c<512); next NB*NMEL -> shiftQ[b][c] (c<80).
__global__ void shifts_kernel(const float* __restrict__ spk, const float* __restrict__ emo,
                              const float* __restrict__ spk_kw, const float* __restrict__ spk_kb,
                              const float* __restrict__ emo_kw, const float* __restrict__ emo_kb,
                              const float* __restrict__ spk_qw, const float* __restrict__ spk_qb,
                              const float* __restrict__ emo_qw, const float* __restrict__ emo_qb,
                              float* __restrict__ shiftK, float* __restrict__ shiftQ) {
    int gw = (blockIdx.x * blockDim.x + threadIdx.x) >> 6;
    int lane = threadIdx.x & 63;
    const int totalK = NB * NTXT, totalQ = NB * NMEL;
    if (gw >= totalK + totalQ) return;
    int b, c; const float *w1, *w2; float bias; float* dst;
    if (gw < totalK) {
        b = gw / NTXT; c = gw % NTXT;
        w1 = spk_kw + (size_t)c * NTXT; w2 = emo_kw + (size_t)c * NTXT;
        bias = spk_kb[c] + emo_kb[c]; dst = shiftK + gw;
    } else {
        int g = gw - totalK; b = g / NMEL; c = g % NMEL;
        w1 = spk_qw + (size_t)c * NTXT; w2 = emo_qw + (size_t)c * NTXT;
        bias = spk_qb[c] + emo_qb[c]; dst = shiftQ + g;
    }
    const float* e1 = spk + (size_t)b * NTXT;
    const float* e2 = emo + (size_t)b * NTXT;
    float acc = 0.f;
    for (int j = lane; j < NTXT; j += 64) acc += e1[j] * w1[j] + e2[j] * w2[j];
    for (int off = 32; off > 0; off >>= 1) acc += __shfl_down(acc, off);
    if (lane == 0) *dst = acc + bias;
}

// ---------------------------------------------------------------------------
// K2/K4: k=3 pad=1 conv, fused per-(b,ci) shift add on input, bias (+relu) on out.
// Tile: 32 oc x 64 t per block (256 thr). CI chunk 16.
__global__ void conv3_kernel(const float* __restrict__ x, const float* __restrict__ w,
                             const float* __restrict__ bias, const float* __restrict__ shift,
                             float* __restrict__ out, int Cin, int Cout, int T, int relu) {
    __shared__ float xs[16][68];       // t0-1 .. t0+64 (66 used)
    __shared__ float wsm[16][3][32];   // [ci][k][oc]
    int b = blockIdx.z;
    int oc0 = blockIdx.y * 32;
    int t0 = blockIdx.x * 64;
    int tid = threadIdx.x;
    int tx = tid & 15;     // t group: t = tx*4 + j
    int ty = tid >> 4;     // oc group: oc = ty*2 + a
    float acc[2][4] = {{0.f,0.f,0.f,0.f},{0.f,0.f,0.f,0.f}};
    for (int ci0 = 0; ci0 < Cin; ci0 += 16) {
        for (int i = tid; i < 16 * 66; i += 256) {
            int ci = i / 66, tt = i % 66;
            int tg = t0 + tt - 1;
            float v = 0.f;
            if (tg >= 0 && tg < T) {
                v = x[((size_t)(b * Cin + ci0 + ci)) * T + tg];
                if (shift) v += shift[b * Cin + ci0 + ci];
            }
            xs[ci][tt] = v;
        }
        for (int i = tid; i < 32 * 48; i += 256) {
            int o = i / 48, r = i % 48, ci = r / 3, k = r % 3;
            wsm[ci][k][o] = w[((size_t)(oc0 + o)) * (Cin * 3) + (ci0 + ci) * 3 + k];
        }
        __syncthreads();
        #pragma unroll
        for (int ci = 0; ci < 16; ++ci) {
            float xv[6];
            #pragma unroll
            for (int j = 0; j < 6; ++j) xv[j] = xs[ci][tx * 4 + j];
            #pragma unroll
            for (int k = 0; k < 3; ++k) {
                float w0 = wsm[ci][k][ty * 2 + 0];
                float w1 = wsm[ci][k][ty * 2 + 1];
                #pragma unroll
                for (int j = 0; j < 4; ++j) {
                    acc[0][j] += w0 * xv[j + k];
                    acc[1][j] += w1 * xv[j + k];
                }
            }
        }
        __syncthreads();
    }
    #pragma unroll
    for (int a = 0; a < 2; ++a) {
        int oc = oc0 + ty * 2 + a;
        float bv = bias[oc];
        #pragma unroll
        for (int j = 0; j < 4; ++j) {
            int tg = t0 + tx * 4 + j;
            if (tg < T) {
                float v = acc[a][j] + bv;
                if (relu) v = fmaxf(v, 0.f);
                out[((size_t)(b * Cout + oc)) * T + tg] = v;
            }
        }
    }
}

// ---------------------------------------------------------------------------
// K3/K5/K6: 1x1 conv, Cout = 80 always. Tile: 80 oc x 64 t per block.
__global__ void conv1x1_kernel(const float* __restrict__ x, const float* __restrict__ w,
                               const float* __restrict__ bias, float* __restrict__ out,
                               int Cin, int T, int relu) {
    __shared__ float xl[16][64];
    __shared__ float wl[16][80];
    int b = blockIdx.y;
    int t0 = blockIdx.x * 64;
    int tid = threadIdx.x;
    int tx = tid & 15;     // t = tx*4 + j
    int ty = tid >> 4;     // oc = ty + 16*o
    float acc[5][4] = {};
    for (int ci0 = 0; ci0 < Cin; ci0 += 16) {
        for (int i = tid; i < 16 * 64; i += 256) {
            int ci = i >> 6, tt = i & 63;
            int tg = t0 + tt;
            xl[ci][tt] = (tg < T) ? x[((size_t)(b * Cin + ci0 + ci)) * T + tg] : 0.f;
        }
        for (int i = tid; i < 80 * 16; i += 256) {
            int o = i >> 4, ci = i & 15;
            wl[ci][o] = w[(size_t)o * Cin + ci0 + ci];
        }
        __syncthreads();
        #pragma unroll
        for (int ci = 0; ci < 16; ++ci) {
            float xv[4];
            #pragma unroll
            for (int j = 0; j < 4; ++j) xv[j] = xl[ci][tx * 4 + j];
            #pragma unroll
            for (int o = 0; o < 5; ++o) {
                float wv = wl[ci][ty + 16 * o];
                #pragma unroll
                for (int j = 0; j < 4; ++j) acc[o][j] += wv * xv[j];
            }
        }
        __syncthreads();
    }
    #pragma unroll
    for (int o = 0; o < 5; ++o) {
        int oc = ty + 16 * o;
        float bv = bias[oc];
        #pragma unroll
        for (int j = 0; j < 4; ++j) {
            int tg = t0 + tx * 4 + j;
            if (tg < T) {
                float v = acc[o][j] + bv;
                if (relu) v = fmaxf(v, 0.f);
                out[((size_t)(b * 80 + oc)) * T + tg] = v;
            }
        }
    }
}

// ---------------------------------------------------------------------------
// K7: per-position sum of squares over channels.
__global__ void sumsq_kernel(const float* __restrict__ x, float* __restrict__ out,
                             int C, int T) {
    int b = blockIdx.y;
    int t = blockIdx.x * 256 + threadIdx.x;
    if (t >= T) return;
    float s = 0.f;
    for (int c = 0; c < C; ++c) {
        float v = x[((size_t)(b * C + c)) * T + t];
        s += v * v;
    }
    out[b * T + t] = s;
}

// ---------------------------------------------------------------------------
// K8: fused QK^T (over 80 ch) + -TEMP*dist^2 + log_softmax + log prior
//     + masked softmax. Block: 256 thr = 4 waves; wave owns 8 full t-rows;
//     lane owns s = lane*4 .. lane*4+3 (all 256 s in one wave).
__global__ void attn_kernel(const float* __restrict__ qenc, const float* __restrict__ kenc,
                            const float* __restrict__ q2, const float* __restrict__ k2,
                            const float* __restrict__ prior, const int* __restrict__ lens,
                            float* __restrict__ out_attn, float* __restrict__ out_lp) {
    __shared__ float kl[16][256];
    __shared__ float ql[16][32];
    int b = blockIdx.y;
    int t0 = blockIdx.x * 32;
    int tid = threadIdx.x;
    int lane = tid & 63;
    int wv = tid >> 6;            // 0..3
    int s0 = lane * 4;
    float acc[8][4] = {};
    for (int ci0 = 0; ci0 < NATT; ci0 += 16) {
        for (int i = tid; i < 16 * 256; i += 256) {
            int ci = i >> 8, s = i & 255;
            kl[ci][s] = kenc[((size_t)(b * NATT + ci0 + ci)) * NT2 + s];
        }
        for (int i = tid; i < 16 * 32; i += 256) {
            int ci = i >> 5, tt = i & 31;
            int tg = t0 + tt;
            ql[ci][tt] = (tg < NT1) ? qenc[((size_t)(b * NATT + ci0 + ci)) * NT1 + tg] : 0.f;
        }
        __syncthreads();
        #pragma unroll
        for (int ci = 0; ci < 16; ++ci) {
            float kv[4];
            #pragma unroll
            for (int j = 0; j < 4; ++j) kv[j] = kl[ci][s0 + j];
            #pragma unroll
            for (int r = 0; r < 8; ++r) {
                float qv = ql[ci][wv * 8 + r];
                #pragma unroll
                for (int j = 0; j < 4; ++j) acc[r][j] += qv * kv[j];
            }
        }
        __syncthreads();
    }
    int len = lens[b];
    float k2v[4];
    #pragma unroll
    for (int j = 0; j < 4; ++j) k2v[j] = k2[b * NT2 + s0 + j];
    #pragma unroll
    for (int r = 0; r < 8; ++r) {
        int t = t0 + wv * 8 + r;          // uniform across the wave
        if (t >= NT1) continue;
        float q2v = q2[b * NT1 + t];
        float lg[4];
        float mx = -INFINITY;
        #pragma unroll
        for (int j = 0; j < 4; ++j) {
            lg[j] = -FTEMP * (q2v + k2v[j] - 2.f * acc[r][j]);
            mx = fmaxf(mx, lg[j]);
        }
        for (int off = 32; off > 0; off >>= 1) mx = fmaxf(mx, __shfl_xor(mx, off));
        float se = 0.f;
        #pragma unroll
        for (int j = 0; j < 4; ++j) se += expf(lg[j] - mx);
        for (int off = 32; off > 0; off >>= 1) se += __shfl_xor(se, off);
        float logZ = mx + logf(se);
        const float* pr = &prior[((size_t)b * NT1 + t) * NT2 + s0];
        float lp[4];
        float mx2 = -INFINITY;
        #pragma unroll
        for (int j = 0; j < 4; ++j) {
            lp[j] = lg[j] - logZ + logf(pr[j] + 1e-8f);
            if (s0 + j < len) mx2 = fmaxf(mx2, lp[j]);
        }
        for (int off = 32; off > 0; off >>= 1) mx2 = fmaxf(mx2, __shfl_xor(mx2, off));
        float se2 = 0.f;
        float ex[4];
        #pragma unroll
        for (int j = 0; j < 4; ++j) {
            ex[j] = (s0 + j < len) ? expf(lp[j] - mx2) : 0.f;
            se2 += ex[j];
        }
        for (int off = 32; off > 0; off >>= 1) se2 += __shfl_xor(se2, off);
        float inv = 1.f / se2;
        size_t o = ((size_t)b * NT1 + t) * NT2 + s0;
        #pragma unroll
        for (int j = 0; j < 4; ++j) {
            out_attn[o + j] = ex[j] * inv;
            out_lp[o + j]   = lp[j];
        }
    }
}

// ---------------------------------------------------------------------------
extern "C" void kernel_launch(void* const* d_in, const int* in_sizes, int n_in,
                              void* d_out, int out_size, void* d_ws, size_t ws_size,
                              hipStream_t stream) {
    (void)in_sizes; (void)n_in; (void)out_size; (void)ws_size;
    const float* queries = (const float*)d_in[0];
    const float* keys    = (const float*)d_in[1];
    const float* prior   = (const float*)d_in[2];
    const float* spk     = (const float*)d_in[3];
    const float* emo     = (const float*)d_in[4];
    const float* kw1     = (const float*)d_in[5];
    const float* kb1     = (const float*)d_in[6];
    const float* kw2     = (const float*)d_in[7];
    const float* kb2     = (const float*)d_in[8];
    const float* qw1     = (const float*)d_in[9];
    const float* qb1     = (const float*)d_in[10];
    const float* qw2     = (const float*)d_in[11];
    const float* qb2     = (const float*)d_in[12];
    const float* qw3     = (const float*)d_in[13];
    const float* qb3     = (const float*)d_in[14];
    const float* spk_kw  = (const float*)d_in[15];
    const float* spk_kb  = (const float*)d_in[16];
    const float* spk_qw  = (const float*)d_in[17];
    const float* spk_qb  = (const float*)d_in[18];
    const float* emo_kw  = (const float*)d_in[19];
    const float* emo_kb  = (const float*)d_in[20];
    const float* emo_qw  = (const float*)d_in[21];
    const float* emo_qb  = (const float*)d_in[22];
    const void*  mask    = d_in[23];

    float* w = (float*)d_ws;
    size_t off = 0;
    float* shiftK = w + off; off += NB * NTXT;            // 4096
    float* shiftQ = w + off; off += NB * NMEL;            // 640
    int*   lens   = (int*)(w + off); off += 16;
    float* kc1    = w + off; off += (size_t)NB * 1024 * NT2;   // 2,097,152
    float* kenc   = w + off; off += (size_t)NB * NATT * NT2;   // 163,840
    float* qc1    = w + off; off += (size_t)NB * 160 * NT1;    // 1,280,000
    float* qc2    = w + off; off += (size_t)NB * NMEL * NT1;   // 640,000
    float* qenc   = w + off; off += (size_t)NB * NATT * NT1;   // 640,000
    float* q2     = w + off; off += NB * NT1;
    float* k2     = w + off; off += NB * NT2;

    float* out_attn = (float*)d_out;
    float* out_lp   = out_attn + (size_t)NB * NT1 * NT2;

    lens_kernel<<<1, 64, 0, stream>>>(mask, lens);

    {   // shifts: (8*512 + 8*80) waves, 4 waves/block
        int waves = NB * NTXT + NB * NMEL;
        shifts_kernel<<<(waves + 3) / 4, 256, 0, stream>>>(
            spk, emo, spk_kw, spk_kb, emo_kw, emo_kb,
            spk_qw, spk_qb, emo_qw, emo_qb, shiftK, shiftQ);
    }

    // keys conv1 (512->1024, T=256, k=3) + shiftK + relu
    conv3_kernel<<<dim3((NT2 + 63) / 64, 1024 / 32, NB), 256, 0, stream>>>(
        keys, kw1, kb1, shiftK, kc1, NTXT, 1024, NT2, 1);
    // keys conv2 (1024->80, 1x1), no relu
    conv1x1_kernel<<<dim3((NT2 + 63) / 64, NB), 256, 0, stream>>>(
        kc1, kw2, kb2, kenc, 1024, NT2, 0);
    // query conv1 (80->160, T=1000, k=3) + shiftQ + relu
    conv3_kernel<<<dim3((NT1 + 63) / 64, 160 / 32, NB), 256, 0, stream>>>(
        queries, qw1, qb1, shiftQ, qc1, NMEL, 160, NT1, 1);
    // query conv2 (160->80, 1x1) + relu
    conv1x1_kernel<<<dim3((NT1 + 63) / 64, NB), 256, 0, stream>>>(
        qc1, qw2, qb2, qc2, 160, NT1, 1);
    // query conv3 (80->80, 1x1), no relu
    conv1x1_kernel<<<dim3((NT1 + 63) / 64, NB), 256, 0, stream>>>(
        qc2, qw3, qb3, qenc, 80, NT1, 0);

    sumsq_kernel<<<dim3((NT1 + 255) / 256, NB), 256, 0, stream>>>(qenc, q2, NATT, NT1);
    sumsq_kernel<<<dim3((NT2 + 255) / 256, NB), 256, 0, stream>>>(kenc, k2, NATT, NT2);

    attn_kernel<<<dim3((NT1 + 31) / 32, NB), 256, 0, stream>>>(
        qenc, kenc, q2, k2, prior, lens, out_attn, out_lp);
}

// Round 2
// 312.906 us; speedup vs baseline: 1.8739x; 1.8739x over previous
//
#include <hip/hip_runtime.h>
#include <math.h>

#define NB   8
#define NMEL 80
#define NTXT 512
#define NATT 80
#define NT1  1000
#define NT2  256
#define FTEMP 0.0005f

typedef __bf16 bf16x8 __attribute__((ext_vector_type(8)));
typedef float  f32x4  __attribute__((ext_vector_type(4)));

__device__ __forceinline__ unsigned short f2bf(float f) {
    unsigned u = __float_as_uint(f);
    unsigned r = (u + 0x7FFFu + ((u >> 16) & 1u)) >> 16;
    return (unsigned short)r;
}

__device__ __forceinline__ void gload_lds16(const void* g, void* l) {
    __builtin_amdgcn_global_load_lds(
        (const __attribute__((address_space(1))) void*)g,
        (__attribute__((address_space(3))) void*)l, 16, 0, 0);
}

// ---------------------------------------------------------------------------
// K0: detect mask storage format, compress monotone mask rows to lengths.
__global__ void lens_kernel(const void* mask, int* lens) {
    int lane = threadIdx.x;  // 64 threads, 1 wave
    const int* mi = (const int*)mask;
    int bf16p = 0, f16p = 0, f32m = 0, big = 0, one = 0;
    for (int i = lane; i < 512; i += 64) {
        unsigned v = (unsigned)mi[i];
        bf16p |= (v == 0x3F803F80u);
        f16p  |= (v == 0x3C003C00u) || (v == 0x3C000000u);
        f32m  |= (v == 0x3F800000u);
        big   |= (v > 1u);
        one   |= (v == 1u);
    }
    bf16p = __any(bf16p); f16p = __any(f16p); f32m = __any(f32m);
    big = __any(big); one = __any(one);
    int mode;
    if (bf16p)      mode = 3;
    else if (f16p)  mode = 4;
    else if (f32m)  mode = 2;
    else if (big)   mode = 0;
    else if (one)   mode = 1;
    else            mode = 5;
    for (int b = 0; b < NB; ++b) {
        int cnt = 0;
        for (int t = lane; t < NT2; t += 64) {
            bool m;
            switch (mode) {
                case 0: m = ((const unsigned char*)mask)[b*NT2 + t] != 0; break;
                case 1: m = ((const int*)mask)[b*NT2 + t] != 0; break;
                case 2: m = ((const float*)mask)[b*NT2 + t] != 0.f; break;
                case 3: case 4: m = ((const unsigned short*)mask)[b*NT2 + t] != 0; break;
                default: m = false; break;
            }
            cnt += m ? 0 : 1;
        }
        for (int off = 32; off > 0; off >>= 1) cnt += __shfl_down(cnt, off);
        if (lane == 0) lens[b] = cnt;
    }
}

// ---------------------------------------------------------------------------
// K1: speaker+emotion channel shifts.
__global__ void shifts_kernel(const float* __restrict__ spk, const float* __restrict__ emo,
                              const float* __restrict__ spk_kw, const float* __restrict__ spk_kb,
                              const float* __restrict__ emo_kw, const float* __restrict__ emo_kb,
                              const float* __restrict__ spk_qw, const float* __restrict__ spk_qb,
                              const float* __restrict__ emo_qw, const float* __restrict__ emo_qb,
                              float* __restrict__ shiftK, float* __restrict__ shiftQ) {
    int gw = (blockIdx.x * blockDim.x + threadIdx.x) >> 6;
    int lane = threadIdx.x & 63;
    const int totalK = NB * NTXT, totalQ = NB * NMEL;
    if (gw >= totalK + totalQ) return;
    int b, c; const float *w1, *w2; float bias; float* dst;
    if (gw < totalK) {
        b = gw / NTXT; c = gw % NTXT;
        w1 = spk_kw + (size_t)c * NTXT; w2 = emo_kw + (size_t)c * NTXT;
        bias = spk_kb[c] + emo_kb[c]; dst = shiftK + gw;
    } else {
        int g = gw - totalK; b = g / NMEL; c = g % NMEL;
        w1 = spk_qw + (size_t)c * NTXT; w2 = emo_qw + (size_t)c * NTXT;
        bias = spk_qb[c] + emo_qb[c]; dst = shiftQ + g;
    }
    const float* e1 = spk + (size_t)b * NTXT;
    const float* e2 = emo + (size_t)b * NTXT;
    float acc = 0.f;
    for (int j = lane; j < NTXT; j += 64) acc += e1[j] * w1[j] + e2[j] * w2[j];
    for (int off = 32; off > 0; off >>= 1) acc += __shfl_down(acc, off);
    if (lane == 0) *dst = acc + bias;
}

// ---------------------------------------------------------------------------
// Prep: kw1 -> bf16 A1 [1024][1536]; kw2 -> bf16 A2 [128][1024] (rows 80+ = 0)
__global__ void prep_weights(const float* __restrict__ kw1, const float* __restrict__ kw2,
                             unsigned short* __restrict__ A1, unsigned short* __restrict__ A2) {
    const int N1 = 1024 * 1536, N2 = 128 * 1024;
    int i = blockIdx.x * 256 + threadIdx.x;
    if (i < N1) {
        A1[i] = f2bf(kw1[i]);
    } else {
        int j = i - N1;
        if (j < N2) {
            int oc = j >> 10;
            A2[j] = (oc < 80) ? f2bf(kw2[j]) : (unsigned short)0;
        }
    }
}

// ---------------------------------------------------------------------------
// Prep: im2col keys (+shift) -> bf16 Bt [N=2048][K=1536], Bt[b*256+t][ci*3+k] =
//       bf16(keys[b][ci][t+k-1] + shiftK[b][ci]) or 0 at borders.
__global__ void im2col_keys(const float* __restrict__ keys, const float* __restrict__ shiftK,
                            unsigned short* __restrict__ Bt) {
    __shared__ float xs[64][67];
    int b = blockIdx.y, t0 = blockIdx.x * 64;
    int tid = threadIdx.x;
    for (int ci0 = 0; ci0 < NTXT; ci0 += 64) {
        for (int i = tid; i < 64 * 66; i += 256) {
            int cis = i / 66, tt = i % 66;
            int tg = t0 + tt - 1;
            float v = 0.f;
            if (tg >= 0 && tg < NT2)
                v = keys[((size_t)(b * NTXT + ci0 + cis)) * NT2 + tg] + shiftK[b * NTXT + ci0 + cis];
            xs[cis][tt] = v;
        }
        __syncthreads();
        for (int i = tid; i < 64 * 64; i += 256) {
            int t = i >> 6, cis = i & 63;
            size_t base = ((size_t)(b * NT2 + t0 + t)) * 1536 + (size_t)(ci0 + cis) * 3;
            Bt[base + 0] = f2bf(xs[cis][t + 0]);
            Bt[base + 1] = f2bf(xs[cis][t + 1]);
            Bt[base + 2] = f2bf(xs[cis][t + 2]);
        }
        __syncthreads();
    }
}

// ---------------------------------------------------------------------------
// bf16 GEMM, C[M,N] = A[M,K] @ B^T[N,K], 128x128 tile, BK=64, 4 waves (2x2).
// EPI=1: out bf16 [N][M], val = relu(acc + bias[m])   (keys conv1 -> kc1bt)
// EPI=0: out f32  [b][80][256] (n=b*256+t), val = acc + bias[m], only m<80.
template<int EPI>
__global__ __launch_bounds__(256)
void gemm_bt(const unsigned short* __restrict__ A, const unsigned short* __restrict__ B,
             const float* __restrict__ bias, void* __restrict__ out,
             int M, int N, int K) {
    __shared__ __attribute__((aligned(16))) unsigned short As[128 * 64];
    __shared__ __attribute__((aligned(16))) unsigned short Bs[128 * 64];
    int m0 = blockIdx.y * 128, n0 = blockIdx.x * 128;
    int tid = threadIdx.x, lane = tid & 63, wv = tid >> 6;
    int wr = wv >> 1, wc = wv & 1;
    f32x4 acc[4][4] = {};
    // staging: chunk = 1KB = 8 rows x 128B; lane l -> row l>>3, swizzled 16B slot
    int srow = lane >> 3;
    int selem = (((lane & 7) * 16) ^ ((srow & 7) << 4)) >> 1;
    for (int k0 = 0; k0 < K; k0 += 64) {
        #pragma unroll
        for (int i = 0; i < 4; ++i) {
            int ch = wv * 4 + i;
            const unsigned short* ga = A + (size_t)(m0 + ch * 8 + srow) * K + k0 + selem;
            gload_lds16(ga, (char*)As + ch * 1024);
            const unsigned short* gb = B + (size_t)(n0 + ch * 8 + srow) * K + k0 + selem;
            gload_lds16(gb, (char*)Bs + ch * 1024);
        }
        __syncthreads();
        #pragma unroll
        for (int ks = 0; ks < 2; ++ks) {
            bf16x8 af[4], bfr[4];
            int kb = (ks * 32 + (lane >> 4) * 8) * 2;
            #pragma unroll
            for (int mi = 0; mi < 4; ++mi) {
                int row = wr * 64 + mi * 16 + (lane & 15);
                int off = row * 128 + (kb ^ ((row & 7) << 4));
                af[mi] = *(const bf16x8*)((const char*)As + off);
            }
            #pragma unroll
            for (int ni = 0; ni < 4; ++ni) {
                int row = wc * 64 + ni * 16 + (lane & 15);
                int off = row * 128 + (kb ^ ((row & 7) << 4));
                bfr[ni] = *(const bf16x8*)((const char*)Bs + off);
            }
            #pragma unroll
            for (int mi = 0; mi < 4; ++mi)
                #pragma unroll
                for (int ni = 0; ni < 4; ++ni)
                    acc[mi][ni] = __builtin_amdgcn_mfma_f32_16x16x32_bf16(af[mi], bfr[ni], acc[mi][ni], 0, 0, 0);
        }
        __syncthreads();
    }
    // epilogue: C row = m0 + wr*64 + mi*16 + (lane>>4)*4 + j ; col = n0 + wc*64 + ni*16 + (lane&15)
    #pragma unroll
    for (int mi = 0; mi < 4; ++mi) {
        #pragma unroll
        for (int ni = 0; ni < 4; ++ni) {
            int mb = m0 + wr * 64 + mi * 16 + (lane >> 4) * 4;
            int n  = n0 + wc * 64 + ni * 16 + (lane & 15);
            if (EPI == 1) {
                unsigned short pk[4];
                #pragma unroll
                for (int j = 0; j < 4; ++j) {
                    float v = acc[mi][ni][j] + bias[mb + j];
                    v = fmaxf(v, 0.f);
                    pk[j] = f2bf(v);
                }
                *(ushort4*)((unsigned short*)out + (size_t)n * M + mb) =
                    make_ushort4(pk[0], pk[1], pk[2], pk[3]);
            } else {
                int b = n >> 8, t = n & 255;
                #pragma unroll
                for (int j = 0; j < 4; ++j) {
                    int m = mb + j;
                    if (m < NATT)
                        ((float*)out)[((size_t)(b * NATT + m)) * NT2 + t] = acc[mi][ni][j] + bias[m];
                }
            }
        }
    }
}

// ---------------------------------------------------------------------------
// K4: k=3 pad=1 conv (queries), fused shift add + bias + relu.
// wsm padded to 33 on oc to kill the 48-way staging bank conflict.
__global__ void conv3_kernel(const float* __restrict__ x, const float* __restrict__ w,
                             const float* __restrict__ bias, const float* __restrict__ shift,
                             float* __restrict__ out, int Cin, int Cout, int T, int relu) {
    __shared__ float xs[16][68];
    __shared__ float wsm[16][3][33];
    int b = blockIdx.z;
    int oc0 = blockIdx.y * 32;
    int t0 = blockIdx.x * 64;
    int tid = threadIdx.x;
    int tx = tid & 15;
    int ty = tid >> 4;
    float acc[2][4] = {{0.f,0.f,0.f,0.f},{0.f,0.f,0.f,0.f}};
    for (int ci0 = 0; ci0 < Cin; ci0 += 16) {
        for (int i = tid; i < 16 * 66; i += 256) {
            int ci = i / 66, tt = i % 66;
            int tg = t0 + tt - 1;
            float v = 0.f;
            if (tg >= 0 && tg < T) {
                v = x[((size_t)(b * Cin + ci0 + ci)) * T + tg];
                if (shift) v += shift[b * Cin + ci0 + ci];
            }
            xs[ci][tt] = v;
        }
        for (int i = tid; i < 32 * 48; i += 256) {
            int o = i / 48, r = i % 48, ci = r / 3, k = r % 3;
            wsm[ci][k][o] = w[((size_t)(oc0 + o)) * (Cin * 3) + (ci0 + ci) * 3 + k];
        }
        __syncthreads();
        #pragma unroll
        for (int ci = 0; ci < 16; ++ci) {
            float xv[6];
            #pragma unroll
            for (int j = 0; j < 6; ++j) xv[j] = xs[ci][tx * 4 + j];
            #pragma unroll
            for (int k = 0; k < 3; ++k) {
                float w0 = wsm[ci][k][ty * 2 + 0];
                float w1 = wsm[ci][k][ty * 2 + 1];
                #pragma unroll
                for (int j = 0; j < 4; ++j) {
                    acc[0][j] += w0 * xv[j + k];
                    acc[1][j] += w1 * xv[j + k];
                }
            }
        }
        __syncthreads();
    }
    #pragma unroll
    for (int a = 0; a < 2; ++a) {
        int oc = oc0 + ty * 2 + a;
        float bv = bias[oc];
        #pragma unroll
        for (int j = 0; j < 4; ++j) {
            int tg = t0 + tx * 4 + j;
            if (tg < T) {
                float v = acc[a][j] + bv;
                if (relu) v = fmaxf(v, 0.f);
                out[((size_t)(b * Cout + oc)) * T + tg] = v;
            }
        }
    }
}

// ---------------------------------------------------------------------------
// 1x1 conv, Cout = 80. Tile: 80 oc x 64 t per block.
__global__ void conv1x1_kernel(const float* __restrict__ x, const float* __restrict__ w,
                               const float* __restrict__ bias, float* __restrict__ out,
                               int Cin, int T, int relu) {
    __shared__ float xl[16][64];
    __shared__ float wl[16][80];
    int b = blockIdx.y;
    int t0 = blockIdx.x * 64;
    int tid = threadIdx.x;
    int tx = tid & 15;
    int ty = tid >> 4;
    float acc[5][4] = {};
    for (int ci0 = 0; ci0 < Cin; ci0 += 16) {
        for (int i = tid; i < 16 * 64; i += 256) {
            int ci = i >> 6, tt = i & 63;
            int tg = t0 + tt;
            xl[ci][tt] = (tg < T) ? x[((size_t)(b * Cin + ci0 + ci)) * T + tg] : 0.f;
        }
        for (int i = tid; i < 80 * 16; i += 256) {
            int o = i >> 4, ci = i & 15;
            wl[ci][o] = w[(size_t)o * Cin + ci0 + ci];
        }
        __syncthreads();
        #pragma unroll
        for (int ci = 0; ci < 16; ++ci) {
            float xv[4];
            #pragma unroll
            for (int j = 0; j < 4; ++j) xv[j] = xl[ci][tx * 4 + j];
            #pragma unroll
            for (int o = 0; o < 5; ++o) {
                float wv = wl[ci][ty + 16 * o];
                #pragma unroll
                for (int j = 0; j < 4; ++j) acc[o][j] += wv * xv[j];
            }
        }
        __syncthreads();
    }
    #pragma unroll
    for (int o = 0; o < 5; ++o) {
        int oc = ty + 16 * o;
        float bv = bias[oc];
        #pragma unroll
        for (int j = 0; j < 4; ++j) {
            int tg = t0 + tx * 4 + j;
            if (tg < T) {
                float v = acc[o][j] + bv;
                if (relu) v = fmaxf(v, 0.f);
                out[((size_t)(b * 80 + oc)) * T + tg] = v;
            }
        }
    }
}

// ---------------------------------------------------------------------------
__global__ void sumsq_kernel(const float* __restrict__ x, float* __restrict__ out,
                             int C, int T) {
    int b = blockIdx.y;
    int t = blockIdx.x * 256 + threadIdx.x;
    if (t >= T) return;
    float s = 0.f;
    for (int c = 0; c < C; ++c) {
        float v = x[((size_t)(b * C + c)) * T + t];
        s += v * v;
    }
    out[b * T + t] = s;
}

// ---------------------------------------------------------------------------
// K8: fused QK^T + dist + log_softmax + log prior + masked softmax.
__global__ void attn_kernel(const float* __restrict__ qenc, const float* __restrict__ kenc,
                            const float* __restrict__ q2, const float* __restrict__ k2,
                            const float* __restrict__ prior, const int* __restrict__ lens,
                            float* __restrict__ out_attn, float* __restrict__ out_lp) {
    __shared__ float kl[16][256];
    __shared__ float ql[16][32];
    int b = blockIdx.y;
    int t0 = blockIdx.x * 32;
    int tid = threadIdx.x;
    int lane = tid & 63;
    int wv = tid >> 6;
    int s0 = lane * 4;
    float acc[8][4] = {};
    for (int ci0 = 0; ci0 < NATT; ci0 += 16) {
        for (int i = tid; i < 16 * 256; i += 256) {
            int ci = i >> 8, s = i & 255;
            kl[ci][s] = kenc[((size_t)(b * NATT + ci0 + ci)) * NT2 + s];
        }
        for (int i = tid; i < 16 * 32; i += 256) {
            int ci = i >> 5, tt = i & 31;
            int tg = t0 + tt;
            ql[ci][tt] = (tg < NT1) ? qenc[((size_t)(b * NATT + ci0 + ci)) * NT1 + tg] : 0.f;
        }
        __syncthreads();
        #pragma unroll
        for (int ci = 0; ci < 16; ++ci) {
            float kv[4];
            #pragma unroll
            for (int j = 0; j < 4; ++j) kv[j] = kl[ci][s0 + j];
            #pragma unroll
            for (int r = 0; r < 8; ++r) {
                float qv = ql[ci][wv * 8 + r];
                #pragma unroll
                for (int j = 0; j < 4; ++j) acc[r][j] += qv * kv[j];
            }
        }
        __syncthreads();
    }
    int len = lens[b];
    float k2v[4];
    #pragma unroll
    for (int j = 0; j < 4; ++j) k2v[j] = k2[b * NT2 + s0 + j];
    #pragma unroll
    for (int r = 0; r < 8; ++r) {
        int t = t0 + wv * 8 + r;
        if (t >= NT1) continue;
        float q2v = q2[b * NT1 + t];
        float lg[4];
        float mx = -INFINITY;
        #pragma unroll
        for (int j = 0; j < 4; ++j) {
            lg[j] = -FTEMP * (q2v + k2v[j] - 2.f * acc[r][j]);
            mx = fmaxf(mx, lg[j]);
        }
        for (int off = 32; off > 0; off >>= 1) mx = fmaxf(mx, __shfl_xor(mx, off));
        float se = 0.f;
        #pragma unroll
        for (int j = 0; j < 4; ++j) se += expf(lg[j] - mx);
        for (int off = 32; off > 0; off >>= 1) se += __shfl_xor(se, off);
        float logZ = mx + logf(se);
        const float* pr = &prior[((size_t)b * NT1 + t) * NT2 + s0];
        float lp[4];
        float mx2 = -INFINITY;
        #pragma unroll
        for (int j = 0; j < 4; ++j) {
            lp[j] = lg[j] - logZ + logf(pr[j] + 1e-8f);
            if (s0 + j < len) mx2 = fmaxf(mx2, lp[j]);
        }
        for (int off = 32; off > 0; off >>= 1) mx2 = fmaxf(mx2, __shfl_xor(mx2, off));
        float se2 = 0.f;
        float ex[4];
        #pragma unroll
        for (int j = 0; j < 4; ++j) {
            ex[j] = (s0 + j < len) ? expf(lp[j] - mx2) : 0.f;
            se2 += ex[j];
        }
        for (int off = 32; off > 0; off >>= 1) se2 += __shfl_xor(se2, off);
        float inv = 1.f / se2;
        size_t o = ((size_t)b * NT1 + t) * NT2 + s0;
        #pragma unroll
        for (int j = 0; j < 4; ++j) {
            out_attn[o + j] = ex[j] * inv;
            out_lp[o + j]   = lp[j];
        }
    }
}

// ---------------------------------------------------------------------------
extern "C" void kernel_launch(void* const* d_in, const int* in_sizes, int n_in,
                              void* d_out, int out_size, void* d_ws, size_t ws_size,
                              hipStream_t stream) {
    (void)in_sizes; (void)n_in; (void)out_size; (void)ws_size;
    const float* queries = (const float*)d_in[0];
    const float* keys    = (const float*)d_in[1];
    const float* prior   = (const float*)d_in[2];
    const float* spk     = (const float*)d_in[3];
    const float* emo     = (const float*)d_in[4];
    const float* kw1     = (const float*)d_in[5];
    const float* kb1     = (const float*)d_in[6];
    const float* kw2     = (const float*)d_in[7];
    const float* kb2     = (const float*)d_in[8];
    const float* qw1     = (const float*)d_in[9];
    const float* qb1     = (const float*)d_in[10];
    const float* qw2     = (const float*)d_in[11];
    const float* qb2     = (const float*)d_in[12];
    const float* qw3     = (const float*)d_in[13];
    const float* qb3     = (const float*)d_in[14];
    const float* spk_kw  = (const float*)d_in[15];
    const float* spk_kb  = (const float*)d_in[16];
    const float* spk_qw  = (const float*)d_in[17];
    const float* spk_qb  = (const float*)d_in[18];
    const float* emo_kw  = (const float*)d_in[19];
    const float* emo_kb  = (const float*)d_in[20];
    const float* emo_qw  = (const float*)d_in[21];
    const float* emo_qb  = (const float*)d_in[22];
    const void*  mask    = d_in[23];

    float* w = (float*)d_ws;
    size_t off = 0;
    float* shiftK = w + off; off += NB * NTXT;                 // 4096
    float* shiftQ = w + off; off += NB * NMEL;                 // 640
    int*   lens   = (int*)(w + off); off += 16;
    float* k2     = w + off; off += NB * NT2;                  // 2048
    float* q2     = w + off; off += NB * NT1;                  // 8000
    float* kenc   = w + off; off += (size_t)NB * NATT * NT2;   // 163,840
    // big region: qc1 [8*160*1000] + qc2 [8*80*1000]; Bt1 (bf16 2048x1536) aliases it
    float* bigreg = w + off;
    float* qc1    = bigreg;
    float* qc2    = bigreg + (size_t)NB * 160 * NT1;
    unsigned short* Bt1 = (unsigned short*)bigreg;             // 3,145,728 ushort <= 1.92M floats
    off += (size_t)NB * 160 * NT1 + (size_t)NB * NMEL * NT1;   // 1,920,000
    float* qenc   = w + off; off += (size_t)NB * NATT * NT1;   // 640,000
    unsigned short* Abf1  = (unsigned short*)(w + off); off += (1024 * 1536) / 2;  // 786,432 floats
    unsigned short* kc1bt = (unsigned short*)(w + off); off += (2048 * 1024) / 2;  // 1,048,576 floats
    unsigned short* Abf2  = (unsigned short*)(w + off); off += (128 * 1024) / 2;   // 65,536 floats

    float* out_attn = (float*)d_out;
    float* out_lp   = out_attn + (size_t)NB * NT1 * NT2;

    lens_kernel<<<1, 64, 0, stream>>>(mask, lens);

    {   // shifts: (8*512 + 8*80) waves, 4 waves/block
        int waves = NB * NTXT + NB * NMEL;
        shifts_kernel<<<(waves + 3) / 4, 256, 0, stream>>>(
            spk, emo, spk_kw, spk_kb, emo_kw, emo_kb,
            spk_qw, spk_qb, emo_qw, emo_qb, shiftK, shiftQ);
    }

    // --- keys path: bf16 MFMA GEMMs ---
    prep_weights<<<(1024 * 1536 + 128 * 1024 + 255) / 256, 256, 0, stream>>>(kw1, kw2, Abf1, Abf2);
    im2col_keys<<<dim3(NT2 / 64, NB), 256, 0, stream>>>(keys, shiftK, Bt1);
    // conv1: C[1024][2048] = A1[1024][1536] @ Bt1^T ; relu+bias -> kc1bt bf16 [2048][1024]
    gemm_bt<1><<<dim3(2048 / 128, 1024 / 128), 256, 0, stream>>>(
        Abf1, Bt1, kb1, kc1bt, 1024, 2048, 1536);
    // conv2: C[80(128)][2048] = A2[128][1024] @ kc1bt^T ; bias -> kenc f32 [8][80][256]
    gemm_bt<0><<<dim3(2048 / 128, 1), 256, 0, stream>>>(
        Abf2, kc1bt, kb2, kenc, 128, 2048, 1024);

    // --- queries path (f32, conv3 bank-conflict fixed) ---
    conv3_kernel<<<dim3((NT1 + 63) / 64, 160 / 32, NB), 256, 0, stream>>>(
        queries, qw1, qb1, shiftQ, qc1, NMEL, 160, NT1, 1);
    conv1x1_kernel<<<dim3((NT1 + 63) / 64, NB), 256, 0, stream>>>(
        qc1, qw2, qb2, qc2, 160, NT1, 1);
    conv1x1_kernel<<<dim3((NT1 + 63) / 64, NB), 256, 0, stream>>>(
        qc2, qw3, qb3, qenc, 80, NT1, 0);

    sumsq_kernel<<<dim3((NT1 + 255) / 256, NB), 256, 0, stream>>>(qenc, q2, NATT, NT1);
    sumsq_kernel<<<dim3((NT2 + 255) / 256, NB), 256, 0, stream>>>(kenc, k2, NATT, NT2);

    attn_kernel<<<dim3((NT1 + 31) / 32, NB), 256, 0, stream>>>(
        qenc, kenc, q2, k2, prior, lens, out_attn, out_lp);
}

// Round 3
// 196.967 us; speedup vs baseline: 2.9770x; 1.5886x over previous
//
#include <hip/hip_runtime.h>
#include <math.h>

#define NB   8
#define NMEL 80
#define NTXT 512
#define NATT 80
#define NT1  1000
#define NT2  256
#define FTEMP 0.0005f

typedef __bf16 bf16x8 __attribute__((ext_vector_type(8)));
typedef float  f32x4  __attribute__((ext_vector_type(4)));

__device__ __forceinline__ unsigned short f2bf(float f) {
    unsigned u = __float_as_uint(f);
    unsigned r = (u + 0x7FFFu + ((u >> 16) & 1u)) >> 16;
    return (unsigned short)r;
}

__device__ __forceinline__ void gload_lds16(const void* g, void* l) {
    __builtin_amdgcn_global_load_lds(
        (const __attribute__((address_space(1))) void*)g,
        (__attribute__((address_space(3))) void*)l, 16, 0, 0);
}

// ---------------------------------------------------------------------------
// K0: detect mask storage format, compress monotone mask rows to lengths.
__global__ void lens_kernel(const void* mask, int* lens) {
    int lane = threadIdx.x;  // 64 threads, 1 wave
    const int* mi = (const int*)mask;
    int bf16p = 0, f16p = 0, f32m = 0, big = 0, one = 0;
    for (int i = lane; i < 512; i += 64) {
        unsigned v = (unsigned)mi[i];
        bf16p |= (v == 0x3F803F80u);
        f16p  |= (v == 0x3C003C00u) || (v == 0x3C000000u);
        f32m  |= (v == 0x3F800000u);
        big   |= (v > 1u);
        one   |= (v == 1u);
    }
    bf16p = __any(bf16p); f16p = __any(f16p); f32m = __any(f32m);
    big = __any(big); one = __any(one);
    int mode;
    if (bf16p)      mode = 3;
    else if (f16p)  mode = 4;
    else if (f32m)  mode = 2;
    else if (big)   mode = 0;
    else if (one)   mode = 1;
    else            mode = 5;
    for (int b = 0; b < NB; ++b) {
        int cnt = 0;
        for (int t = lane; t < NT2; t += 64) {
            bool m;
            switch (mode) {
                case 0: m = ((const unsigned char*)mask)[b*NT2 + t] != 0; break;
                case 1: m = ((const int*)mask)[b*NT2 + t] != 0; break;
                case 2: m = ((const float*)mask)[b*NT2 + t] != 0.f; break;
                case 3: case 4: m = ((const unsigned short*)mask)[b*NT2 + t] != 0; break;
                default: m = false; break;
            }
            cnt += m ? 0 : 1;
        }
        for (int off = 32; off > 0; off >>= 1) cnt += __shfl_down(cnt, off);
        if (lane == 0) lens[b] = cnt;
    }
}

// ---------------------------------------------------------------------------
// K1: speaker+emotion channel shifts.
__global__ void shifts_kernel(const float* __restrict__ spk, const float* __restrict__ emo,
                              const float* __restrict__ spk_kw, const float* __restrict__ spk_kb,
                              const float* __restrict__ emo_kw, const float* __restrict__ emo_kb,
                              const float* __restrict__ spk_qw, const float* __restrict__ spk_qb,
                              const float* __restrict__ emo_qw, const float* __restrict__ emo_qb,
                              float* __restrict__ shiftK, float* __restrict__ shiftQ) {
    int gw = (blockIdx.x * blockDim.x + threadIdx.x) >> 6;
    int lane = threadIdx.x & 63;
    const int totalK = NB * NTXT, totalQ = NB * NMEL;
    if (gw >= totalK + totalQ) return;
    int b, c; const float *w1, *w2; float bias; float* dst;
    if (gw < totalK) {
        b = gw / NTXT; c = gw % NTXT;
        w1 = spk_kw + (size_t)c * NTXT; w2 = emo_kw + (size_t)c * NTXT;
        bias = spk_kb[c] + emo_kb[c]; dst = shiftK + gw;
    } else {
        int g = gw - totalK; b = g / NMEL; c = g % NMEL;
        w1 = spk_qw + (size_t)c * NTXT; w2 = emo_qw + (size_t)c * NTXT;
        bias = spk_qb[c] + emo_qb[c]; dst = shiftQ + g;
    }
    const float* e1 = spk + (size_t)b * NTXT;
    const float* e2 = emo + (size_t)b * NTXT;
    float acc = 0.f;
    for (int j = lane; j < NTXT; j += 64) acc += e1[j] * w1[j] + e2[j] * w2[j];
    for (int off = 32; off > 0; off >>= 1) acc += __shfl_down(acc, off);
    if (lane == 0) *dst = acc + bias;
}

// ---------------------------------------------------------------------------
// Prep: all weights -> padded bf16 matrices + padded biases.
// Abf1 [1024][1536]=kw1 ; Abf2 [128][1024]=kw2 (rows>=80 zero)
// A1q [256][256]: rows<160, cols<240 = qw1 ; A2q [128][256]: rows<80, cols<160 = qw2
// A3q [128][128]: rows<80, cols<80 = qw3 ; pqb1[256] (qb1,pad0) ; pqb2[128] (qb2,pad0)
__global__ void prep_weights(const float* __restrict__ kw1, const float* __restrict__ kw2,
                             const float* __restrict__ qw1, const float* __restrict__ qw2,
                             const float* __restrict__ qw3, const float* __restrict__ qb1,
                             const float* __restrict__ qb2,
                             unsigned short* __restrict__ Abf1, unsigned short* __restrict__ Abf2,
                             unsigned short* __restrict__ A1q, unsigned short* __restrict__ A2q,
                             unsigned short* __restrict__ A3q,
                             float* __restrict__ pqb1, float* __restrict__ pqb2) {
    int i = blockIdx.x * 256 + threadIdx.x;
    const int n0 = 1024 * 1536, n1 = 128 * 1024, n2 = 256 * 256, n3 = 128 * 256, n4 = 128 * 128;
    if (i < n0) { Abf1[i] = f2bf(kw1[i]); return; }
    i -= n0;
    if (i < n1) { int oc = i >> 10; Abf2[i] = (oc < 80) ? f2bf(kw2[i]) : (unsigned short)0; return; }
    i -= n1;
    if (i < n2) { int m = i >> 8, c = i & 255;
                  A1q[i] = (m < 160 && c < 240) ? f2bf(qw1[m * 240 + c]) : (unsigned short)0; return; }
    i -= n2;
    if (i < n3) { int m = i >> 8, c = i & 255;
                  A2q[i] = (m < 80 && c < 160) ? f2bf(qw2[m * 160 + c]) : (unsigned short)0; return; }
    i -= n3;
    if (i < n4) { int m = i >> 7, c = i & 127;
                  A3q[i] = (m < 80 && c < 80) ? f2bf(qw3[m * 80 + c]) : (unsigned short)0; return; }
    i -= n4;
    if (i < 256) { pqb1[i] = (i < 160) ? qb1[i] : 0.f; return; }
    i -= 256;
    if (i < 128) { pqb2[i] = (i < 80) ? qb2[i] : 0.f; return; }
}

// ---------------------------------------------------------------------------
// im2col keys (+shift) -> bf16 Bt [2048][1536]. Grid (4, NB, 8): z = ci-chunk.
__global__ void im2col_keys(const float* __restrict__ keys, const float* __restrict__ shiftK,
                            unsigned short* __restrict__ Bt) {
    __shared__ float xs[64][67];
    int b = blockIdx.y, t0 = blockIdx.x * 64, ci0 = blockIdx.z * 64;
    int tid = threadIdx.x;
    for (int i = tid; i < 64 * 66; i += 256) {
        int cis = i / 66, tt = i % 66;
        int tg = t0 + tt - 1;
        float v = 0.f;
        if (tg >= 0 && tg < NT2)
            v = keys[((size_t)(b * NTXT + ci0 + cis)) * NT2 + tg] + shiftK[b * NTXT + ci0 + cis];
        xs[cis][tt] = v;
    }
    __syncthreads();
    for (int i = tid; i < 64 * 64; i += 256) {
        int t = i >> 6, cis = i & 63;
        size_t base = ((size_t)(b * NT2 + t0 + t)) * 1536 + (size_t)(ci0 + cis) * 3;
        Bt[base + 0] = f2bf(xs[cis][t + 0]);
        Bt[base + 1] = f2bf(xs[cis][t + 1]);
        Bt[base + 2] = f2bf(xs[cis][t + 2]);
    }
}

// ---------------------------------------------------------------------------
// im2col queries (+shift) -> bf16 Bt [8064][256] (240 real cols, zero pad).
// Rows 8000..8063 zeroed by the (b==7, last tile) block. Grid (16, NB).
__global__ void im2col_q(const float* __restrict__ q, const float* __restrict__ shiftQ,
                         unsigned short* __restrict__ Bt) {
    __shared__ float xs[80][67];
    int b = blockIdx.y, t0 = blockIdx.x * 64;
    int tid = threadIdx.x;
    for (int i = tid; i < 80 * 66; i += 256) {
        int cis = i / 66, tt = i % 66;
        int tg = t0 + tt - 1;
        float v = 0.f;
        if (tg >= 0 && tg < NT1)
            v = q[((size_t)(b * NMEL + cis)) * NT1 + tg] + shiftQ[b * NMEL + cis];
        xs[cis][tt] = v;
    }
    __syncthreads();
    for (int i = tid; i < 64 * 80; i += 256) {
        int t = i / 80, cis = i % 80;
        int tg = t0 + t;
        if (tg < NT1) {
            size_t base = ((size_t)(b * NT1 + tg)) * 256 + (size_t)cis * 3;
            Bt[base + 0] = f2bf(xs[cis][t + 0]);
            Bt[base + 1] = f2bf(xs[cis][t + 1]);
            Bt[base + 2] = f2bf(xs[cis][t + 2]);
        }
    }
    for (int i = tid; i < 64 * 4; i += 256) {       // zero cols 240..255
        int t = i >> 2, seg = i & 3;
        int tg = t0 + t;
        if (tg < NT1)
            *(ushort4*)(Bt + ((size_t)(b * NT1 + tg)) * 256 + 240 + seg * 4) =
                make_ushort4(0, 0, 0, 0);
    }
    if (b == NB - 1 && blockIdx.x == 15) {          // zero pad rows 8000..8063
        for (int i = tid; i < 64 * 32; i += 256) {
            int r = i >> 5, c = (i & 31) * 8;
            *(ushort4*)(Bt + (size_t)(8000 + r) * 256 + c) = make_ushort4(0, 0, 0, 0);
            *(ushort4*)(Bt + (size_t)(8000 + r) * 256 + c + 4) = make_ushort4(0, 0, 0, 0);
        }
    }
}

// ---------------------------------------------------------------------------
// bf16 GEMM, C = A[Mpad,K] @ B^T[Npad,K], tile 128x64, BK=64, 4 waves (2x2).
// EPI=1: out bf16 [n][M], val = relu(acc + bias[m])
// EPI=0: out f32 [b][80][T] with n = b*T+t, guard n<Nreal, m<80: acc + bias[m]
template<int EPI>
__global__ __launch_bounds__(256)
void gemm_bt(const unsigned short* __restrict__ A, const unsigned short* __restrict__ B,
             const float* __restrict__ bias, void* __restrict__ out,
             int M, int K, int T, int Nreal) {
    __shared__ __attribute__((aligned(16))) unsigned short As[128 * 64];
    __shared__ __attribute__((aligned(16))) unsigned short Bs[64 * 64];
    int m0 = blockIdx.y * 128, n0 = blockIdx.x * 64;
    int tid = threadIdx.x, lane = tid & 63, wv = tid >> 6;
    int wr = wv >> 1, wc = wv & 1;
    f32x4 acc[4][2] = {};
    int srow = lane >> 3;
    int selem = (((lane & 7) * 16) ^ ((srow & 7) << 4)) >> 1;
    for (int k0 = 0; k0 < K; k0 += 64) {
        #pragma unroll
        for (int i = 0; i < 4; ++i) {
            int ch = wv * 4 + i;   // 16 A-chunks of 8 rows
            gload_lds16(A + (size_t)(m0 + ch * 8 + srow) * K + k0 + selem, (char*)As + ch * 1024);
        }
        #pragma unroll
        for (int i = 0; i < 2; ++i) {
            int ch = wv * 2 + i;   // 8 B-chunks of 8 rows
            gload_lds16(B + (size_t)(n0 + ch * 8 + srow) * K + k0 + selem, (char*)Bs + ch * 1024);
        }
        __syncthreads();
        #pragma unroll
        for (int ks = 0; ks < 2; ++ks) {
            bf16x8 af[4], bfr[2];
            int kb = ks * 64 + (lane >> 4) * 16;   // byte offset of 8-bf16 group
            #pragma unroll
            for (int mi = 0; mi < 4; ++mi) {
                int row = wr * 64 + mi * 16 + (lane & 15);
                af[mi] = *(const bf16x8*)((const char*)As + row * 128 + (kb ^ ((row & 7) << 4)));
            }
            #pragma unroll
            for (int ni = 0; ni < 2; ++ni) {
                int row = wc * 32 + ni * 16 + (lane & 15);
                bfr[ni] = *(const bf16x8*)((const char*)Bs + row * 128 + (kb ^ ((row & 7) << 4)));
            }
            #pragma unroll
            for (int mi = 0; mi < 4; ++mi)
                #pragma unroll
                for (int ni = 0; ni < 2; ++ni)
                    acc[mi][ni] = __builtin_amdgcn_mfma_f32_16x16x32_bf16(af[mi], bfr[ni], acc[mi][ni], 0, 0, 0);
        }
        __syncthreads();
    }
    #pragma unroll
    for (int mi = 0; mi < 4; ++mi) {
        #pragma unroll
        for (int ni = 0; ni < 2; ++ni) {
            int mb = m0 + wr * 64 + mi * 16 + (lane >> 4) * 4;
            int n  = n0 + wc * 32 + ni * 16 + (lane & 15);
            if (EPI == 1) {
                unsigned short pk[4];
                #pragma unroll
                for (int j = 0; j < 4; ++j) {
                    float v = acc[mi][ni][j] + bias[mb + j];
                    pk[j] = f2bf(fmaxf(v, 0.f));
                }
                *(ushort4*)((unsigned short*)out + (size_t)n * M + mb) =
                    make_ushort4(pk[0], pk[1], pk[2], pk[3]);
            } else {
                if (n < Nreal) {
                    int b = n / T, t = n - b * T;
                    #pragma unroll
                    for (int j = 0; j < 4; ++j) {
                        int m = mb + j;
                        if (m < NATT)
                            ((float*)out)[((size_t)(b * NATT + m)) * T + t] = acc[mi][ni][j] + bias[m];
                    }
                }
            }
        }
    }
}

// ---------------------------------------------------------------------------
__global__ void sumsq_kernel(const float* __restrict__ x, float* __restrict__ out,
                             int C, int T) {
    int b = blockIdx.y;
    int t = blockIdx.x * 256 + threadIdx.x;
    if (t >= T) return;
    float s = 0.f;
    for (int c = 0; c < C; ++c) {
        float v = x[((size_t)(b * C + c)) * T + t];
        s += v * v;
    }
    out[b * T + t] = s;
}

// ---------------------------------------------------------------------------
// K8: fused QK^T + dist + log_softmax + log prior + masked softmax.
__global__ void attn_kernel(const float* __restrict__ qenc, const float* __restrict__ kenc,
                            const float* __restrict__ q2, const float* __restrict__ k2,
                            const float* __restrict__ prior, const int* __restrict__ lens,
                            float* __restrict__ out_attn, float* __restrict__ out_lp) {
    __shared__ float kl[16][256];
    __shared__ float ql[16][32];
    int b = blockIdx.y;
    int t0 = blockIdx.x * 32;
    int tid = threadIdx.x;
    int lane = tid & 63;
    int wv = tid >> 6;
    int s0 = lane * 4;
    float acc[8][4] = {};
    for (int ci0 = 0; ci0 < NATT; ci0 += 16) {
        for (int i = tid; i < 16 * 256; i += 256) {
            int ci = i >> 8, s = i & 255;
            kl[ci][s] = kenc[((size_t)(b * NATT + ci0 + ci)) * NT2 + s];
        }
        for (int i = tid; i < 16 * 32; i += 256) {
            int ci = i >> 5, tt = i & 31;
            int tg = t0 + tt;
            ql[ci][tt] = (tg < NT1) ? qenc[((size_t)(b * NATT + ci0 + ci)) * NT1 + tg] : 0.f;
        }
        __syncthreads();
        #pragma unroll
        for (int ci = 0; ci < 16; ++ci) {
            float kv[4];
            #pragma unroll
            for (int j = 0; j < 4; ++j) kv[j] = kl[ci][s0 + j];
            #pragma unroll
            for (int r = 0; r < 8; ++r) {
                float qv = ql[ci][wv * 8 + r];
                #pragma unroll
                for (int j = 0; j < 4; ++j) acc[r][j] += qv * kv[j];
            }
        }
        __syncthreads();
    }
    int len = lens[b];
    float k2v[4];
    #pragma unroll
    for (int j = 0; j < 4; ++j) k2v[j] = k2[b * NT2 + s0 + j];
    #pragma unroll
    for (int r = 0; r < 8; ++r) {
        int t = t0 + wv * 8 + r;
        if (t >= NT1) continue;
        float q2v = q2[b * NT1 + t];
        float lg[4];
        float mx = -INFINITY;
        #pragma unroll
        for (int j = 0; j < 4; ++j) {
            lg[j] = -FTEMP * (q2v + k2v[j] - 2.f * acc[r][j]);
            mx = fmaxf(mx, lg[j]);
        }
        for (int off = 32; off > 0; off >>= 1) mx = fmaxf(mx, __shfl_xor(mx, off));
        float se = 0.f;
        #pragma unroll
        for (int j = 0; j < 4; ++j) se += expf(lg[j] - mx);
        for (int off = 32; off > 0; off >>= 1) se += __shfl_xor(se, off);
        float logZ = mx + logf(se);
        const float* pr = &prior[((size_t)b * NT1 + t) * NT2 + s0];
        float lp[4];
        float mx2 = -INFINITY;
        #pragma unroll
        for (int j = 0; j < 4; ++j) {
            lp[j] = lg[j] - logZ + logf(pr[j] + 1e-8f);
            if (s0 + j < len) mx2 = fmaxf(mx2, lp[j]);
        }
        for (int off = 32; off > 0; off >>= 1) mx2 = fmaxf(mx2, __shfl_xor(mx2, off));
        float se2 = 0.f;
        float ex[4];
        #pragma unroll
        for (int j = 0; j < 4; ++j) {
            ex[j] = (s0 + j < len) ? expf(lp[j] - mx2) : 0.f;
            se2 += ex[j];
        }
        for (int off = 32; off > 0; off >>= 1) se2 += __shfl_xor(se2, off);
        float inv = 1.f / se2;
        size_t o = ((size_t)b * NT1 + t) * NT2 + s0;
        #pragma unroll
        for (int j = 0; j < 4; ++j) {
            out_attn[o + j] = ex[j] * inv;
            out_lp[o + j]   = lp[j];
        }
    }
}

// ---------------------------------------------------------------------------
extern "C" void kernel_launch(void* const* d_in, const int* in_sizes, int n_in,
                              void* d_out, int out_size, void* d_ws, size_t ws_size,
                              hipStream_t stream) {
    (void)in_sizes; (void)n_in; (void)out_size; (void)ws_size;
    const float* queries = (const float*)d_in[0];
    const float* keys    = (const float*)d_in[1];
    const float* prior   = (const float*)d_in[2];
    const float* spk     = (const float*)d_in[3];
    const float* emo     = (const float*)d_in[4];
    const float* kw1     = (const float*)d_in[5];
    const float* kb1     = (const float*)d_in[6];
    const float* kw2     = (const float*)d_in[7];
    const float* kb2     = (const float*)d_in[8];
    const float* qw1     = (const float*)d_in[9];
    const float* qb1     = (const float*)d_in[10];
    const float* qw2     = (const float*)d_in[11];
    const float* qb2     = (const float*)d_in[12];
    const float* qw3     = (const float*)d_in[13];
    const float* qb3     = (const float*)d_in[14];
    const float* spk_kw  = (const float*)d_in[15];
    const float* spk_kb  = (const float*)d_in[16];
    const float* spk_qw  = (const float*)d_in[17];
    const float* spk_qb  = (const float*)d_in[18];
    const float* emo_kw  = (const float*)d_in[19];
    const float* emo_kb  = (const float*)d_in[20];
    const float* emo_qw  = (const float*)d_in[21];
    const float* emo_qb  = (const float*)d_in[22];
    const void*  mask    = d_in[23];

    float* w = (float*)d_ws;
    size_t off = 0;
    float* shiftK = w + off; off += NB * NTXT;                 // 4096
    float* shiftQ = w + off; off += NB * NMEL;                 // 640
    int*   lens   = (int*)(w + off); off += 16;
    float* k2     = w + off; off += NB * NT2;                  // 2048
    float* q2     = w + off; off += NB * NT1;                  // 8000
    float* kenc   = w + off; off += (size_t)NB * NATT * NT2;   // 163,840
    // R1: Bt1 (keys im2col, 2048x1536 us = 1,572,864 fl); later Btq (8064x256 us
    //     = 1,032,192 fl) followed by qc2bt (8064x128 us = 516,096 fl) -> 1,548,288 fl. Fits.
    float* R1 = w + off; off += (size_t)2048 * 1536 / 2;
    unsigned short* Bt1   = (unsigned short*)R1;
    unsigned short* Btq   = (unsigned short*)R1;
    unsigned short* qc2bt = (unsigned short*)R1 + (size_t)8064 * 256;
    // R2: kc1bt (2048x1024 us = 1,048,576 fl); later qc1bt (8064x256 us = 1,032,192 fl). Fits.
    float* R2 = w + off; off += (size_t)2048 * 1024 / 2;
    unsigned short* kc1bt = (unsigned short*)R2;
    unsigned short* qc1bt = (unsigned short*)R2;
    float* qenc = w + off; off += (size_t)NB * NATT * NT1;     // 640,000
    unsigned short* Abf1 = (unsigned short*)(w + off); off += (size_t)1024 * 1536 / 2;
    unsigned short* Abf2 = (unsigned short*)(w + off); off += (size_t)128 * 1024 / 2;
    unsigned short* A1q  = (unsigned short*)(w + off); off += (size_t)256 * 256 / 2;
    unsigned short* A2q  = (unsigned short*)(w + off); off += (size_t)128 * 256 / 2;
    unsigned short* A3q  = (unsigned short*)(w + off); off += (size_t)128 * 128 / 2;
    float* pqb1 = w + off; off += 256;
    float* pqb2 = w + off; off += 128;

    float* out_attn = (float*)d_out;
    float* out_lp   = out_attn + (size_t)NB * NT1 * NT2;

    lens_kernel<<<1, 64, 0, stream>>>(mask, lens);

    {   // shifts: (8*512 + 8*80) waves, 4 waves/block
        int waves = NB * NTXT + NB * NMEL;
        shifts_kernel<<<(waves + 3) / 4, 256, 0, stream>>>(
            spk, emo, spk_kw, spk_kb, emo_kw, emo_kb,
            spk_qw, spk_qb, emo_qw, emo_qb, shiftK, shiftQ);
    }

    {   // weight prep (all padded bf16 matrices + padded biases)
        int total = 1024 * 1536 + 128 * 1024 + 256 * 256 + 128 * 256 + 128 * 128 + 256 + 128;
        prep_weights<<<(total + 255) / 256, 256, 0, stream>>>(
            kw1, kw2, qw1, qw2, qw3, qb1, qb2,
            Abf1, Abf2, A1q, A2q, A3q, pqb1, pqb2);
    }

    // --- keys path ---
    im2col_keys<<<dim3(NT2 / 64, NB, NTXT / 64), 256, 0, stream>>>(keys, shiftK, Bt1);
    // conv1: [1024][2048] = Abf1 @ Bt1^T ; bias+relu -> kc1bt bf16 [2048][1024]
    gemm_bt<1><<<dim3(2048 / 64, 1024 / 128), 256, 0, stream>>>(
        Abf1, Bt1, kb1, kc1bt, 1024, 1536, 0, 0);
    // conv2: [80][2048] = Abf2 @ kc1bt^T ; bias -> kenc f32 [8][80][256]
    gemm_bt<0><<<dim3(2048 / 64, 1), 256, 0, stream>>>(
        Abf2, kc1bt, kb2, kenc, 128, 1024, NT2, 2048);

    // --- queries path ---
    im2col_q<<<dim3(16, NB), 256, 0, stream>>>(queries, shiftQ, Btq);
    // conv1: [160][8000] -> qc1bt bf16 [8064][256], bias+relu
    gemm_bt<1><<<dim3(8064 / 64, 2), 256, 0, stream>>>(
        A1q, Btq, pqb1, qc1bt, 256, 256, 0, 0);
    // conv2: [80][8000] -> qc2bt bf16 [8064][128], bias+relu
    gemm_bt<1><<<dim3(8064 / 64, 1), 256, 0, stream>>>(
        A2q, qc1bt, pqb2, qc2bt, 128, 256, 0, 0);
    // conv3: [80][8000] -> qenc f32 [8][80][1000], bias
    gemm_bt<0><<<dim3(8064 / 64, 1), 256, 0, stream>>>(
        A3q, qc2bt, qb3, qenc, 128, 128, NT1, 8000);

    sumsq_kernel<<<dim3((NT1 + 255) / 256, NB), 256, 0, stream>>>(qenc, q2, NATT, NT1);
    sumsq_kernel<<<dim3((NT2 + 255) / 256, NB), 256, 0, stream>>>(kenc, k2, NATT, NT2);

    attn_kernel<<<dim3((NT1 + 31) / 32, NB), 256, 0, stream>>>(
        qenc, kenc, q2, k2, prior, lens, out_attn, out_lp);
}

// Round 4
// 123.816 us; speedup vs baseline: 4.7357x; 1.5908x over previous
//
#include <hip/hip_runtime.h>
#include <math.h>

#define NB   8
#define NMEL 80
#define NTXT 512
#define NATT 80
#define NT1  1000
#define NT2  256
#define FTEMP 0.0005f

typedef __bf16 bf16x8 __attribute__((ext_vector_type(8)));
typedef float  f32x4  __attribute__((ext_vector_type(4)));

__device__ __forceinline__ unsigned short f2bf(float f) {
    unsigned u = __float_as_uint(f);
    unsigned r = (u + 0x7FFFu + ((u >> 16) & 1u)) >> 16;
    return (unsigned short)r;
}

__device__ __forceinline__ void gload_lds16(const void* g, void* l) {
    __builtin_amdgcn_global_load_lds(
        (const __attribute__((address_space(1))) void*)g,
        (__attribute__((address_space(3))) void*)l, 16, 0, 0);
}

// ---------------------------------------------------------------------------
// prep_all: [weights-cast blocks | shifts blocks | lens block]
#define PW_TOTAL (1024*1536 + 128*1024 + 256*256 + 128*256 + 128*128 + 256 + 128)
#define PW_BLOCKS ((PW_TOTAL + 255) / 256)          // 7106
#define SH_WAVES  (NB * NTXT + NB * NMEL)           // 4736
#define SH_BLOCKS ((SH_WAVES + 3) / 4)              // 1184

__global__ void prep_all(const float* __restrict__ kw1, const float* __restrict__ kw2,
                         const float* __restrict__ qw1, const float* __restrict__ qw2,
                         const float* __restrict__ qw3, const float* __restrict__ qb1,
                         const float* __restrict__ qb2,
                         unsigned short* __restrict__ Abf1, unsigned short* __restrict__ Abf2,
                         unsigned short* __restrict__ A1q, unsigned short* __restrict__ A2q,
                         unsigned short* __restrict__ A3q,
                         float* __restrict__ pqb1, float* __restrict__ pqb2,
                         const float* __restrict__ spk, const float* __restrict__ emo,
                         const float* __restrict__ spk_kw, const float* __restrict__ spk_kb,
                         const float* __restrict__ emo_kw, const float* __restrict__ emo_kb,
                         const float* __restrict__ spk_qw, const float* __restrict__ spk_qb,
                         const float* __restrict__ emo_qw, const float* __restrict__ emo_qb,
                         float* __restrict__ shiftK, float* __restrict__ shiftQ,
                         const void* __restrict__ mask, int* __restrict__ lens) {
    int bx = blockIdx.x, tid = threadIdx.x;
    if (bx < PW_BLOCKS) {
        int i = bx * 256 + tid;
        const int n0 = 1024 * 1536, n1 = 128 * 1024, n2 = 256 * 256, n3 = 128 * 256, n4 = 128 * 128;
        if (i < n0) { Abf1[i] = f2bf(kw1[i]); return; }
        i -= n0;
        if (i < n1) { int oc = i >> 10; Abf2[i] = (oc < 80) ? f2bf(kw2[i]) : (unsigned short)0; return; }
        i -= n1;
        if (i < n2) { int m = i >> 8, c = i & 255;
                      A1q[i] = (m < 160 && c < 240) ? f2bf(qw1[m * 240 + c]) : (unsigned short)0; return; }
        i -= n2;
        if (i < n3) { int m = i >> 8, c = i & 255;
                      A2q[i] = (m < 80 && c < 160) ? f2bf(qw2[m * 160 + c]) : (unsigned short)0; return; }
        i -= n3;
        if (i < n4) { int m = i >> 7, c = i & 127;
                      A3q[i] = (m < 80 && c < 80) ? f2bf(qw3[m * 80 + c]) : (unsigned short)0; return; }
        i -= n4;
        if (i < 256) { pqb1[i] = (i < 160) ? qb1[i] : 0.f; return; }
        i -= 256;
        if (i < 128) { pqb2[i] = (i < 80) ? qb2[i] : 0.f; }
        return;
    }
    bx -= PW_BLOCKS;
    if (bx < SH_BLOCKS) {
        int gw = bx * 4 + (tid >> 6);
        int lane = tid & 63;
        const int totalK = NB * NTXT, totalQ = NB * NMEL;
        if (gw >= totalK + totalQ) return;
        int b, c; const float *w1, *w2; float bias; float* dst;
        if (gw < totalK) {
            b = gw / NTXT; c = gw % NTXT;
            w1 = spk_kw + (size_t)c * NTXT; w2 = emo_kw + (size_t)c * NTXT;
            bias = spk_kb[c] + emo_kb[c]; dst = shiftK + gw;
        } else {
            int g = gw - totalK; b = g / NMEL; c = g % NMEL;
            w1 = spk_qw + (size_t)c * NTXT; w2 = emo_qw + (size_t)c * NTXT;
            bias = spk_qb[c] + emo_qb[c]; dst = shiftQ + g;
        }
        const float* e1 = spk + (size_t)b * NTXT;
        const float* e2 = emo + (size_t)b * NTXT;
        float acc = 0.f;
        for (int j = lane; j < NTXT; j += 64) acc += e1[j] * w1[j] + e2[j] * w2[j];
        for (int off = 32; off > 0; off >>= 1) acc += __shfl_down(acc, off);
        if (lane == 0) *dst = acc + bias;
        return;
    }
    // lens: one wave
    if (tid >= 64) return;
    int lane = tid;
    const int* mi = (const int*)mask;
    int bf16p = 0, f16p = 0, f32m = 0, big = 0, one = 0;
    for (int i = lane; i < 512; i += 64) {
        unsigned v = (unsigned)mi[i];
        bf16p |= (v == 0x3F803F80u);
        f16p  |= (v == 0x3C003C00u) || (v == 0x3C000000u);
        f32m  |= (v == 0x3F800000u);
        big   |= (v > 1u);
        one   |= (v == 1u);
    }
    bf16p = __any(bf16p); f16p = __any(f16p); f32m = __any(f32m);
    big = __any(big); one = __any(one);
    int mode;
    if (bf16p)      mode = 3;
    else if (f16p)  mode = 4;
    else if (f32m)  mode = 2;
    else if (big)   mode = 0;
    else if (one)   mode = 1;
    else            mode = 5;
    for (int b = 0; b < NB; ++b) {
        int cnt = 0;
        for (int t = lane; t < NT2; t += 64) {
            bool m;
            switch (mode) {
                case 0: m = ((const unsigned char*)mask)[b*NT2 + t] != 0; break;
                case 1: m = ((const int*)mask)[b*NT2 + t] != 0; break;
                case 2: m = ((const float*)mask)[b*NT2 + t] != 0.f; break;
                case 3: case 4: m = ((const unsigned short*)mask)[b*NT2 + t] != 0; break;
                default: m = false; break;
            }
            cnt += m ? 0 : 1;
        }
        for (int off = 32; off > 0; off >>= 1) cnt += __shfl_down(cnt, off);
        if (lane == 0) lens[b] = cnt;
    }
}

// ---------------------------------------------------------------------------
// im2col_all: blocks 0..255 keys -> Bt1 [2048][1536]; 256..383 queries -> Btq [8064][256]
__global__ void im2col_all(const float* __restrict__ keys, const float* __restrict__ shiftK,
                           unsigned short* __restrict__ Bt1,
                           const float* __restrict__ q, const float* __restrict__ shiftQ,
                           unsigned short* __restrict__ Btq) {
    __shared__ float xs[80 * 67];
    int bx = blockIdx.x, tid = threadIdx.x;
    if (bx < 256) {
        int x = bx & 3, b = (bx >> 2) & 7, z = bx >> 5;
        int t0 = x * 64, ci0 = z * 64;
        for (int i = tid; i < 64 * 66; i += 256) {
            int cis = i / 66, tt = i % 66;
            int tg = t0 + tt - 1;
            float v = 0.f;
            if (tg >= 0 && tg < NT2)
                v = keys[((size_t)(b * NTXT + ci0 + cis)) * NT2 + tg] + shiftK[b * NTXT + ci0 + cis];
            xs[cis * 67 + tt] = v;
        }
        __syncthreads();
        for (int i = tid; i < 64 * 64; i += 256) {
            int t = i >> 6, cis = i & 63;
            size_t base = ((size_t)(b * NT2 + t0 + t)) * 1536 + (size_t)(ci0 + cis) * 3;
            Bt1[base + 0] = f2bf(xs[cis * 67 + t + 0]);
            Bt1[base + 1] = f2bf(xs[cis * 67 + t + 1]);
            Bt1[base + 2] = f2bf(xs[cis * 67 + t + 2]);
        }
        return;
    }
    int qb = bx - 256;
    int x = qb & 15, b = qb >> 4;
    int t0 = x * 64;
    for (int i = tid; i < 80 * 66; i += 256) {
        int cis = i / 66, tt = i % 66;
        int tg = t0 + tt - 1;
        float v = 0.f;
        if (tg >= 0 && tg < NT1)
            v = q[((size_t)(b * NMEL + cis)) * NT1 + tg] + shiftQ[b * NMEL + cis];
        xs[cis * 67 + tt] = v;
    }
    __syncthreads();
    for (int i = tid; i < 64 * 80; i += 256) {
        int t = i / 80, cis = i % 80;
        int tg = t0 + t;
        if (tg < NT1) {
            size_t base = ((size_t)(b * NT1 + tg)) * 256 + (size_t)cis * 3;
            Btq[base + 0] = f2bf(xs[cis * 67 + t + 0]);
            Btq[base + 1] = f2bf(xs[cis * 67 + t + 1]);
            Btq[base + 2] = f2bf(xs[cis * 67 + t + 2]);
        }
    }
    for (int i = tid; i < 64 * 4; i += 256) {       // zero cols 240..255
        int t = i >> 2, seg = i & 3;
        int tg = t0 + t;
        if (tg < NT1)
            *(ushort4*)(Btq + ((size_t)(b * NT1 + tg)) * 256 + 240 + seg * 4) =
                make_ushort4(0, 0, 0, 0);
    }
    if (b == NB - 1 && x == 15) {                   // zero pad rows 8000..8063
        for (int i = tid; i < 64 * 32; i += 256) {
            int r = i >> 5, c = (i & 31) * 8;
            *(ushort4*)(Btq + (size_t)(8000 + r) * 256 + c) = make_ushort4(0, 0, 0, 0);
            *(ushort4*)(Btq + (size_t)(8000 + r) * 256 + c + 4) = make_ushort4(0, 0, 0, 0);
        }
    }
}

// ---------------------------------------------------------------------------
// Device GEMM: C = A[Mpad,K] @ B^T[Npad,K], tile 128x64, BK=64, 4 waves (2x2).
// EPI=1: out bf16 [n][M], relu(acc+bias[m]).
// EPI=0: out f32 [b][80][T], n=b*T+t guard n<Nreal, m<80; SSQ=1 also writes
//        ssq[n] = sum_{m<80} v^2 (per-column, reduced via shfl+LDS).
template<int EPI, int SSQ>
__device__ __forceinline__ void gemm_dev(
        const unsigned short* __restrict__ A, const unsigned short* __restrict__ B,
        const float* __restrict__ bias, void* __restrict__ out, float* __restrict__ ssq,
        int M, int K, int T, int Nreal, int m0, int n0,
        unsigned short* As, unsigned short* Bs, float* red) {
    int tid = threadIdx.x, lane = tid & 63, wv = tid >> 6;
    int wr = wv >> 1, wc = wv & 1;
    f32x4 acc[4][2] = {};
    int srow = lane >> 3;
    int selem = (((lane & 7) * 16) ^ ((srow & 7) << 4)) >> 1;
    for (int k0 = 0; k0 < K; k0 += 64) {
        #pragma unroll
        for (int i = 0; i < 4; ++i) {
            int ch = wv * 4 + i;
            gload_lds16(A + (size_t)(m0 + ch * 8 + srow) * K + k0 + selem, (char*)As + ch * 1024);
        }
        #pragma unroll
        for (int i = 0; i < 2; ++i) {
            int ch = wv * 2 + i;
            gload_lds16(B + (size_t)(n0 + ch * 8 + srow) * K + k0 + selem, (char*)Bs + ch * 1024);
        }
        __syncthreads();
        #pragma unroll
        for (int ks = 0; ks < 2; ++ks) {
            bf16x8 af[4], bfr[2];
            int kb = ks * 64 + (lane >> 4) * 16;
            #pragma unroll
            for (int mi = 0; mi < 4; ++mi) {
                int row = wr * 64 + mi * 16 + (lane & 15);
                af[mi] = *(const bf16x8*)((const char*)As + row * 128 + (kb ^ ((row & 7) << 4)));
            }
            #pragma unroll
            for (int ni = 0; ni < 2; ++ni) {
                int row = wc * 32 + ni * 16 + (lane & 15);
                bfr[ni] = *(const bf16x8*)((const char*)Bs + row * 128 + (kb ^ ((row & 7) << 4)));
            }
            #pragma unroll
            for (int mi = 0; mi < 4; ++mi)
                #pragma unroll
                for (int ni = 0; ni < 2; ++ni)
                    acc[mi][ni] = __builtin_amdgcn_mfma_f32_16x16x32_bf16(af[mi], bfr[ni], acc[mi][ni], 0, 0, 0);
        }
        __syncthreads();
    }
    if (EPI == 1) {
        #pragma unroll
        for (int mi = 0; mi < 4; ++mi) {
            #pragma unroll
            for (int ni = 0; ni < 2; ++ni) {
                int mb = m0 + wr * 64 + mi * 16 + (lane >> 4) * 4;
                int n  = n0 + wc * 32 + ni * 16 + (lane & 15);
                unsigned short pk[4];
                #pragma unroll
                for (int j = 0; j < 4; ++j) {
                    float v = acc[mi][ni][j] + bias[mb + j];
                    pk[j] = f2bf(fmaxf(v, 0.f));
                }
                *(ushort4*)((unsigned short*)out + (size_t)n * M + mb) =
                    make_ushort4(pk[0], pk[1], pk[2], pk[3]);
            }
        }
    } else {
        float part[2] = {0.f, 0.f};
        #pragma unroll
        for (int mi = 0; mi < 4; ++mi) {
            #pragma unroll
            for (int ni = 0; ni < 2; ++ni) {
                int mb = wr * 64 + mi * 16 + (lane >> 4) * 4;   // m0 == 0 for EPI=0
                int n  = n0 + wc * 32 + ni * 16 + (lane & 15);
                bool nok = (n < Nreal);
                int b = n / T, t = n - b * T;
                #pragma unroll
                for (int j = 0; j < 4; ++j) {
                    int m = mb + j;
                    if (m < NATT) {
                        float v = acc[mi][ni][j] + bias[m];
                        part[ni] += v * v;
                        if (nok)
                            ((float*)out)[((size_t)(b * NATT + m)) * T + t] = v;
                    }
                }
            }
        }
        if (SSQ) {
            #pragma unroll
            for (int ni = 0; ni < 2; ++ni) {
                part[ni] += __shfl_xor(part[ni], 16);
                part[ni] += __shfl_xor(part[ni], 32);
            }
            if ((lane >> 4) == 0) {
                red[wr * 64 + wc * 32 + (lane & 15)]      = part[0];
                red[wr * 64 + wc * 32 + 16 + (lane & 15)] = part[1];
            }
            __syncthreads();
            if (tid < 64) {
                int n = n0 + tid;
                if (n < Nreal) ssq[n] = red[tid] + red[64 + tid];
            }
        }
    }
}

// ---------------------------------------------------------------------------
// stage1: keys conv1 (256 blocks) || queries conv1 (252 blocks)
__global__ __launch_bounds__(256)
void gemm_stage1(const unsigned short* __restrict__ Abf1, const unsigned short* __restrict__ Bt1,
                 const float* __restrict__ kb1, unsigned short* __restrict__ kc1bt,
                 const unsigned short* __restrict__ A1q, const unsigned short* __restrict__ Btq,
                 const float* __restrict__ pqb1, unsigned short* __restrict__ qc1bt) {
    __shared__ __attribute__((aligned(16))) unsigned short As[128 * 64];
    __shared__ __attribute__((aligned(16))) unsigned short Bs[64 * 64];
    int bx = blockIdx.x;
    if (bx < 256) {
        int y = bx >> 5, x = bx & 31;
        gemm_dev<1, 0>(Abf1, Bt1, kb1, kc1bt, nullptr, 1024, 1536, 0, 0,
                       y * 128, x * 64, As, Bs, nullptr);
    } else {
        int q = bx - 256;
        int y = q / 126, x = q - y * 126;
        gemm_dev<1, 0>(A1q, Btq, pqb1, qc1bt, nullptr, 256, 256, 0, 0,
                       y * 128, x * 64, As, Bs, nullptr);
    }
}

// stage2: keys conv2 + k2 (32 blocks) || queries conv2 (126 blocks)
__global__ __launch_bounds__(256)
void gemm_stage2(const unsigned short* __restrict__ Abf2, const unsigned short* __restrict__ kc1bt,
                 const float* __restrict__ kb2, float* __restrict__ kenc, float* __restrict__ k2,
                 const unsigned short* __restrict__ A2q, const unsigned short* __restrict__ qc1bt,
                 const float* __restrict__ pqb2, unsigned short* __restrict__ qc2bt) {
    __shared__ __attribute__((aligned(16))) unsigned short As[128 * 64];
    __shared__ __attribute__((aligned(16))) unsigned short Bs[64 * 64];
    __shared__ float red[128];
    int bx = blockIdx.x;
    if (bx < 32) {
        gemm_dev<0, 1>(Abf2, kc1bt, kb2, kenc, k2, 128, 1024, NT2, 2048,
                       0, bx * 64, As, Bs, red);
    } else {
        gemm_dev<1, 0>(A2q, qc1bt, pqb2, qc2bt, nullptr, 128, 256, 0, 0,
                       0, (bx - 32) * 64, As, Bs, nullptr);
    }
}

// stage3: queries conv3 + q2 (126 blocks)
__global__ __launch_bounds__(256)
void gemm_stage3(const unsigned short* __restrict__ A3q, const unsigned short* __restrict__ qc2bt,
                 const float* __restrict__ qb3, float* __restrict__ qenc, float* __restrict__ q2) {
    __shared__ __attribute__((aligned(16))) unsigned short As[128 * 64];
    __shared__ __attribute__((aligned(16))) unsigned short Bs[64 * 64];
    __shared__ float red[128];
    gemm_dev<0, 1>(A3q, qc2bt, qb3, qenc, q2, 128, 128, NT1, 8000,
                   0, blockIdx.x * 64, As, Bs, red);
}

// ---------------------------------------------------------------------------
// attn: fused QK^T + dist + log_softmax + log prior + masked softmax.
__global__ void attn_kernel(const float* __restrict__ qenc, const float* __restrict__ kenc,
                            const float* __restrict__ q2, const float* __restrict__ k2,
                            const float* __restrict__ prior, const int* __restrict__ lens,
                            float* __restrict__ out_attn, float* __restrict__ out_lp) {
    __shared__ float kl[16][256];
    __shared__ float ql[16][32];
    int b = blockIdx.y;
    int t0 = blockIdx.x * 32;
    int tid = threadIdx.x;
    int lane = tid & 63;
    int wv = tid >> 6;
    int s0 = lane * 4;
    float acc[8][4] = {};
    for (int ci0 = 0; ci0 < NATT; ci0 += 16) {
        for (int i = tid; i < 16 * 256; i += 256) {
            int ci = i >> 8, s = i & 255;
            kl[ci][s] = kenc[((size_t)(b * NATT + ci0 + ci)) * NT2 + s];
        }
        for (int i = tid; i < 16 * 32; i += 256) {
            int ci = i >> 5, tt = i & 31;
            int tg = t0 + tt;
            ql[ci][tt] = (tg < NT1) ? qenc[((size_t)(b * NATT + ci0 + ci)) * NT1 + tg] : 0.f;
        }
        __syncthreads();
        #pragma unroll
        for (int ci = 0; ci < 16; ++ci) {
            float kv[4];
            #pragma unroll
            for (int j = 0; j < 4; ++j) kv[j] = kl[ci][s0 + j];
            #pragma unroll
            for (int r = 0; r < 8; ++r) {
                float qv = ql[ci][wv * 8 + r];
                #pragma unroll
                for (int j = 0; j < 4; ++j) acc[r][j] += qv * kv[j];
            }
        }
        __syncthreads();
    }
    int len = lens[b];
    float k2v[4];
    #pragma unroll
    for (int j = 0; j < 4; ++j) k2v[j] = k2[b * NT2 + s0 + j];
    #pragma unroll
    for (int r = 0; r < 8; ++r) {
        int t = t0 + wv * 8 + r;
        if (t >= NT1) continue;
        float q2v = q2[b * NT1 + t];
        float lg[4];
        float mx = -INFINITY;
        #pragma unroll
        for (int j = 0; j < 4; ++j) {
            lg[j] = -FTEMP * (q2v + k2v[j] - 2.f * acc[r][j]);
            mx = fmaxf(mx, lg[j]);
        }
        for (int off = 32; off > 0; off >>= 1) mx = fmaxf(mx, __shfl_xor(mx, off));
        float se = 0.f;
        #pragma unroll
        for (int j = 0; j < 4; ++j) se += __expf(lg[j] - mx);
        for (int off = 32; off > 0; off >>= 1) se += __shfl_xor(se, off);
        float logZ = mx + __logf(se);
        const float* pr = &prior[((size_t)b * NT1 + t) * NT2 + s0];
        float lp[4];
        float mx2 = -INFINITY;
        #pragma unroll
        for (int j = 0; j < 4; ++j) {
            lp[j] = lg[j] - logZ + __logf(pr[j] + 1e-8f);
            if (s0 + j < len) mx2 = fmaxf(mx2, lp[j]);
        }
        for (int off = 32; off > 0; off >>= 1) mx2 = fmaxf(mx2, __shfl_xor(mx2, off));
        float se2 = 0.f;
        float ex[4];
        #pragma unroll
        for (int j = 0; j < 4; ++j) {
            ex[j] = (s0 + j < len) ? __expf(lp[j] - mx2) : 0.f;
            se2 += ex[j];
        }
        for (int off = 32; off > 0; off >>= 1) se2 += __shfl_xor(se2, off);
        float inv = 1.f / se2;
        size_t o = ((size_t)b * NT1 + t) * NT2 + s0;
        #pragma unroll
        for (int j = 0; j < 4; ++j) {
            out_attn[o + j] = ex[j] * inv;
            out_lp[o + j]   = lp[j];
        }
    }
}

// ---------------------------------------------------------------------------
extern "C" void kernel_launch(void* const* d_in, const int* in_sizes, int n_in,
                              void* d_out, int out_size, void* d_ws, size_t ws_size,
                              hipStream_t stream) {
    (void)in_sizes; (void)n_in; (void)out_size; (void)ws_size;
    const float* queries = (const float*)d_in[0];
    const float* keys    = (const float*)d_in[1];
    const float* prior   = (const float*)d_in[2];
    const float* spk     = (const float*)d_in[3];
    const float* emo     = (const float*)d_in[4];
    const float* kw1     = (const float*)d_in[5];
    const float* kb1     = (const float*)d_in[6];
    const float* kw2     = (const float*)d_in[7];
    const float* kb2     = (const float*)d_in[8];
    const float* qw1     = (const float*)d_in[9];
    const float* qb1     = (const float*)d_in[10];
    const float* qw2     = (const float*)d_in[11];
    const float* qb2     = (const float*)d_in[12];
    const float* qw3     = (const float*)d_in[13];
    const float* qb3     = (const float*)d_in[14];
    const float* spk_kw  = (const float*)d_in[15];
    const float* spk_kb  = (const float*)d_in[16];
    const float* spk_qw  = (const float*)d_in[17];
    const float* spk_qb  = (const float*)d_in[18];
    const float* emo_kw  = (const float*)d_in[19];
    const float* emo_kb  = (const float*)d_in[20];
    const float* emo_qw  = (const float*)d_in[21];
    const float* emo_qb  = (const float*)d_in[22];
    const void*  mask    = d_in[23];

    float* w = (float*)d_ws;
    size_t off = 0;
    float* shiftK = w + off; off += NB * NTXT;
    float* shiftQ = w + off; off += NB * NMEL;
    int*   lens   = (int*)(w + off); off += 16;
    float* k2     = w + off; off += NB * NT2;
    float* q2     = w + off; off += NB * NT1;
    float* kenc   = w + off; off += (size_t)NB * NATT * NT2;
    float* qenc   = w + off; off += (size_t)NB * NATT * NT1;
    unsigned short* Bt1   = (unsigned short*)(w + off); off += (size_t)2048 * 1536 / 2;
    unsigned short* kc1bt = (unsigned short*)(w + off); off += (size_t)2048 * 1024 / 2;
    unsigned short* Btq   = (unsigned short*)(w + off); off += (size_t)8064 * 256 / 2;
    unsigned short* qc1bt = (unsigned short*)(w + off); off += (size_t)8064 * 256 / 2;
    unsigned short* qc2bt = (unsigned short*)(w + off); off += (size_t)8064 * 128 / 2;
    unsigned short* Abf1  = (unsigned short*)(w + off); off += (size_t)1024 * 1536 / 2;
    unsigned short* Abf2  = (unsigned short*)(w + off); off += (size_t)128 * 1024 / 2;
    unsigned short* A1q   = (unsigned short*)(w + off); off += (size_t)256 * 256 / 2;
    unsigned short* A2q   = (unsigned short*)(w + off); off += (size_t)128 * 256 / 2;
    unsigned short* A3q   = (unsigned short*)(w + off); off += (size_t)128 * 128 / 2;
    float* pqb1 = w + off; off += 256;
    float* pqb2 = w + off; off += 128;

    float* out_attn = (float*)d_out;
    float* out_lp   = out_attn + (size_t)NB * NT1 * NT2;

    // 1: all prep (lens + shifts + weight casts)
    prep_all<<<PW_BLOCKS + SH_BLOCKS + 1, 256, 0, stream>>>(
        kw1, kw2, qw1, qw2, qw3, qb1, qb2,
        Abf1, Abf2, A1q, A2q, A3q, pqb1, pqb2,
        spk, emo, spk_kw, spk_kb, emo_kw, emo_kb,
        spk_qw, spk_qb, emo_qw, emo_qb, shiftK, shiftQ,
        mask, lens);

    // 2: both im2cols
    im2col_all<<<384, 256, 0, stream>>>(keys, shiftK, Bt1, queries, shiftQ, Btq);

    // 3: keys conv1 || queries conv1
    gemm_stage1<<<508, 256, 0, stream>>>(Abf1, Bt1, kb1, kc1bt, A1q, Btq, pqb1, qc1bt);

    // 4: keys conv2 (+k2) || queries conv2
    gemm_stage2<<<158, 256, 0, stream>>>(Abf2, kc1bt, kb2, kenc, k2, A2q, qc1bt, pqb2, qc2bt);

    // 5: queries conv3 (+q2)
    gemm_stage3<<<126, 256, 0, stream>>>(A3q, qc2bt, qb3, qenc, q2);

    // 6: fused attention
    attn_kernel<<<dim3((NT1 + 31) / 32, NB), 256, 0, stream>>>(
        qenc, kenc, q2, k2, prior, lens, out_attn, out_lp);
}

// Round 5
// 112.911 us; speedup vs baseline: 5.1931x; 1.0966x over previous
//
#include <hip/hip_runtime.h>
#include <math.h>

#define NB   8
#define NMEL 80
#define NTXT 512
#define NATT 80
#define NT1  1000
#define NT2  256
#define FTEMP 0.0005f

typedef __bf16 bf16x8 __attribute__((ext_vector_type(8)));
typedef float  f32x4  __attribute__((ext_vector_type(4)));

__device__ __forceinline__ unsigned short f2bf(float f) {
    unsigned u = __float_as_uint(f);
    unsigned r = (u + 0x7FFFu + ((u >> 16) & 1u)) >> 16;
    return (unsigned short)r;
}

__device__ __forceinline__ void gload_lds16(const void* g, void* l) {
    __builtin_amdgcn_global_load_lds(
        (const __attribute__((address_space(1))) void*)g,
        (__attribute__((address_space(3))) void*)l, 16, 0, 0);
}

// ---------------------------------------------------------------------------
// prep_all: [weights-cast blocks | shifts blocks | lens block]
#define PW_TOTAL (1024*1536 + 128*1024 + 256*256 + 128*256 + 128*128 + 256 + 128)
#define PW_BLOCKS ((PW_TOTAL + 255) / 256)          // 7106
#define SH_WAVES  (NB * NTXT + NB * NMEL)           // 4736
#define SH_BLOCKS ((SH_WAVES + 3) / 4)              // 1184

__global__ void prep_all(const float* __restrict__ kw1, const float* __restrict__ kw2,
                         const float* __restrict__ qw1, const float* __restrict__ qw2,
                         const float* __restrict__ qw3, const float* __restrict__ qb1,
                         const float* __restrict__ qb2,
                         unsigned short* __restrict__ Abf1, unsigned short* __restrict__ Abf2,
                         unsigned short* __restrict__ A1q, unsigned short* __restrict__ A2q,
                         unsigned short* __restrict__ A3q,
                         float* __restrict__ pqb1, float* __restrict__ pqb2,
                         const float* __restrict__ spk, const float* __restrict__ emo,
                         const float* __restrict__ spk_kw, const float* __restrict__ spk_kb,
                         const float* __restrict__ emo_kw, const float* __restrict__ emo_kb,
                         const float* __restrict__ spk_qw, const float* __restrict__ spk_qb,
                         const float* __restrict__ emo_qw, const float* __restrict__ emo_qb,
                         float* __restrict__ shiftK, float* __restrict__ shiftQ,
                         const void* __restrict__ mask, int* __restrict__ lens) {
    int bx = blockIdx.x, tid = threadIdx.x;
    if (bx < PW_BLOCKS) {
        int i = bx * 256 + tid;
        const int n0 = 1024 * 1536, n1 = 128 * 1024, n2 = 256 * 256, n3 = 128 * 256, n4 = 128 * 128;
        if (i < n0) { Abf1[i] = f2bf(kw1[i]); return; }
        i -= n0;
        if (i < n1) { int oc = i >> 10; Abf2[i] = (oc < 80) ? f2bf(kw2[i]) : (unsigned short)0; return; }
        i -= n1;
        if (i < n2) { int m = i >> 8, c = i & 255;
                      A1q[i] = (m < 160 && c < 240) ? f2bf(qw1[m * 240 + c]) : (unsigned short)0; return; }
        i -= n2;
        if (i < n3) { int m = i >> 8, c = i & 255;
                      A2q[i] = (m < 80 && c < 160) ? f2bf(qw2[m * 160 + c]) : (unsigned short)0; return; }
        i -= n3;
        if (i < n4) { int m = i >> 7, c = i & 127;
                      A3q[i] = (m < 80 && c < 80) ? f2bf(qw3[m * 80 + c]) : (unsigned short)0; return; }
        i -= n4;
        if (i < 256) { pqb1[i] = (i < 160) ? qb1[i] : 0.f; return; }
        i -= 256;
        if (i < 128) { pqb2[i] = (i < 80) ? qb2[i] : 0.f; }
        return;
    }
    bx -= PW_BLOCKS;
    if (bx < SH_BLOCKS) {
        int gw = bx * 4 + (tid >> 6);
        int lane = tid & 63;
        const int totalK = NB * NTXT, totalQ = NB * NMEL;
        if (gw >= totalK + totalQ) return;
        int b, c; const float *w1, *w2; float bias; float* dst;
        if (gw < totalK) {
            b = gw / NTXT; c = gw % NTXT;
            w1 = spk_kw + (size_t)c * NTXT; w2 = emo_kw + (size_t)c * NTXT;
            bias = spk_kb[c] + emo_kb[c]; dst = shiftK + gw;
        } else {
            int g = gw - totalK; b = g / NMEL; c = g % NMEL;
            w1 = spk_qw + (size_t)c * NTXT; w2 = emo_qw + (size_t)c * NTXT;
            bias = spk_qb[c] + emo_qb[c]; dst = shiftQ + g;
        }
        const float* e1 = spk + (size_t)b * NTXT;
        const float* e2 = emo + (size_t)b * NTXT;
        float acc = 0.f;
        for (int j = lane; j < NTXT; j += 64) acc += e1[j] * w1[j] + e2[j] * w2[j];
        for (int off = 32; off > 0; off >>= 1) acc += __shfl_down(acc, off);
        if (lane == 0) *dst = acc + bias;
        return;
    }
    // lens: one wave
    if (tid >= 64) return;
    int lane = tid;
    const int* mi = (const int*)mask;
    int bf16p = 0, f16p = 0, f32m = 0, big = 0, one = 0;
    for (int i = lane; i < 512; i += 64) {
        unsigned v = (unsigned)mi[i];
        bf16p |= (v == 0x3F803F80u);
        f16p  |= (v == 0x3C003C00u) || (v == 0x3C000000u);
        f32m  |= (v == 0x3F800000u);
        big   |= (v > 1u);
        one   |= (v == 1u);
    }
    bf16p = __any(bf16p); f16p = __any(f16p); f32m = __any(f32m);
    big = __any(big); one = __any(one);
    int mode;
    if (bf16p)      mode = 3;
    else if (f16p)  mode = 4;
    else if (f32m)  mode = 2;
    else if (big)   mode = 0;
    else if (one)   mode = 1;
    else            mode = 5;
    for (int b = 0; b < NB; ++b) {
        int cnt = 0;
        for (int t = lane; t < NT2; t += 64) {
            bool m;
            switch (mode) {
                case 0: m = ((const unsigned char*)mask)[b*NT2 + t] != 0; break;
                case 1: m = ((const int*)mask)[b*NT2 + t] != 0; break;
                case 2: m = ((const float*)mask)[b*NT2 + t] != 0.f; break;
                case 3: case 4: m = ((const unsigned short*)mask)[b*NT2 + t] != 0; break;
                default: m = false; break;
            }
            cnt += m ? 0 : 1;
        }
        for (int off = 32; off > 0; off >>= 1) cnt += __shfl_down(cnt, off);
        if (lane == 0) lens[b] = cnt;
    }
}

// ---------------------------------------------------------------------------
// im2col_all: blocks 0..255 keys -> Bt1 [2048][1536]; 256..383 queries -> Btq [8064][256]
__global__ void im2col_all(const float* __restrict__ keys, const float* __restrict__ shiftK,
                           unsigned short* __restrict__ Bt1,
                           const float* __restrict__ q, const float* __restrict__ shiftQ,
                           unsigned short* __restrict__ Btq) {
    __shared__ float xs[80 * 67];
    int bx = blockIdx.x, tid = threadIdx.x;
    if (bx < 256) {
        int x = bx & 3, b = (bx >> 2) & 7, z = bx >> 5;
        int t0 = x * 64, ci0 = z * 64;
        for (int i = tid; i < 64 * 66; i += 256) {
            int cis = i / 66, tt = i % 66;
            int tg = t0 + tt - 1;
            float v = 0.f;
            if (tg >= 0 && tg < NT2)
                v = keys[((size_t)(b * NTXT + ci0 + cis)) * NT2 + tg] + shiftK[b * NTXT + ci0 + cis];
            xs[cis * 67 + tt] = v;
        }
        __syncthreads();
        for (int i = tid; i < 64 * 64; i += 256) {
            int t = i >> 6, cis = i & 63;
            size_t base = ((size_t)(b * NT2 + t0 + t)) * 1536 + (size_t)(ci0 + cis) * 3;
            Bt1[base + 0] = f2bf(xs[cis * 67 + t + 0]);
            Bt1[base + 1] = f2bf(xs[cis * 67 + t + 1]);
            Bt1[base + 2] = f2bf(xs[cis * 67 + t + 2]);
        }
        return;
    }
    int qb = bx - 256;
    int x = qb & 15, b = qb >> 4;
    int t0 = x * 64;
    for (int i = tid; i < 80 * 66; i += 256) {
        int cis = i / 66, tt = i % 66;
        int tg = t0 + tt - 1;
        float v = 0.f;
        if (tg >= 0 && tg < NT1)
            v = q[((size_t)(b * NMEL + cis)) * NT1 + tg] + shiftQ[b * NMEL + cis];
        xs[cis * 67 + tt] = v;
    }
    __syncthreads();
    for (int i = tid; i < 64 * 80; i += 256) {
        int t = i / 80, cis = i % 80;
        int tg = t0 + t;
        if (tg < NT1) {
            size_t base = ((size_t)(b * NT1 + tg)) * 256 + (size_t)cis * 3;
            Btq[base + 0] = f2bf(xs[cis * 67 + t + 0]);
            Btq[base + 1] = f2bf(xs[cis * 67 + t + 1]);
            Btq[base + 2] = f2bf(xs[cis * 67 + t + 2]);
        }
    }
    for (int i = tid; i < 64 * 4; i += 256) {       // zero cols 240..255
        int t = i >> 2, seg = i & 3;
        int tg = t0 + t;
        if (tg < NT1)
            *(ushort4*)(Btq + ((size_t)(b * NT1 + tg)) * 256 + 240 + seg * 4) =
                make_ushort4(0, 0, 0, 0);
    }
    if (b == NB - 1 && x == 15) {                   // zero pad rows 8000..8063
        for (int i = tid; i < 64 * 32; i += 256) {
            int r = i >> 5, c = (i & 31) * 8;
            *(ushort4*)(Btq + (size_t)(8000 + r) * 256 + c) = make_ushort4(0, 0, 0, 0);
            *(ushort4*)(Btq + (size_t)(8000 + r) * 256 + c + 4) = make_ushort4(0, 0, 0, 0);
        }
    }
}

// ---------------------------------------------------------------------------
// Device GEMM: C = A[Mpad,K] @ B^T[Npad,K], tile 128x64, BK=64, 4 waves (2x2).
// EPI=1: out bf16 [n][M], relu(acc+bias[m]).
// EPI=0: out f32 [b][80][T], n=b*T+t guard n<Nreal, m<80; SSQ=1 also writes
//        ssq[n] = sum_{m<80} v^2 (per-column, reduced via shfl+LDS).
template<int EPI, int SSQ>
__device__ __forceinline__ void gemm_dev(
        const unsigned short* __restrict__ A, const unsigned short* __restrict__ B,
        const float* __restrict__ bias, void* __restrict__ out, float* __restrict__ ssq,
        int M, int K, int T, int Nreal, int m0, int n0,
        unsigned short* As, unsigned short* Bs, float* red) {
    int tid = threadIdx.x, lane = tid & 63, wv = tid >> 6;
    int wr = wv >> 1, wc = wv & 1;
    f32x4 acc[4][2] = {};
    int srow = lane >> 3;
    int selem = (((lane & 7) * 16) ^ ((srow & 7) << 4)) >> 1;
    for (int k0 = 0; k0 < K; k0 += 64) {
        #pragma unroll
        for (int i = 0; i < 4; ++i) {
            int ch = wv * 4 + i;
            gload_lds16(A + (size_t)(m0 + ch * 8 + srow) * K + k0 + selem, (char*)As + ch * 1024);
        }
        #pragma unroll
        for (int i = 0; i < 2; ++i) {
            int ch = wv * 2 + i;
            gload_lds16(B + (size_t)(n0 + ch * 8 + srow) * K + k0 + selem, (char*)Bs + ch * 1024);
        }
        __syncthreads();
        #pragma unroll
        for (int ks = 0; ks < 2; ++ks) {
            bf16x8 af[4], bfr[2];
            int kb = ks * 64 + (lane >> 4) * 16;
            #pragma unroll
            for (int mi = 0; mi < 4; ++mi) {
                int row = wr * 64 + mi * 16 + (lane & 15);
                af[mi] = *(const bf16x8*)((const char*)As + row * 128 + (kb ^ ((row & 7) << 4)));
            }
            #pragma unroll
            for (int ni = 0; ni < 2; ++ni) {
                int row = wc * 32 + ni * 16 + (lane & 15);
                bfr[ni] = *(const bf16x8*)((const char*)Bs + row * 128 + (kb ^ ((row & 7) << 4)));
            }
            #pragma unroll
            for (int mi = 0; mi < 4; ++mi)
                #pragma unroll
                for (int ni = 0; ni < 2; ++ni)
                    acc[mi][ni] = __builtin_amdgcn_mfma_f32_16x16x32_bf16(af[mi], bfr[ni], acc[mi][ni], 0, 0, 0);
        }
        __syncthreads();
    }
    if (EPI == 1) {
        #pragma unroll
        for (int mi = 0; mi < 4; ++mi) {
            #pragma unroll
            for (int ni = 0; ni < 2; ++ni) {
                int mb = m0 + wr * 64 + mi * 16 + (lane >> 4) * 4;
                int n  = n0 + wc * 32 + ni * 16 + (lane & 15);
                unsigned short pk[4];
                #pragma unroll
                for (int j = 0; j < 4; ++j) {
                    float v = acc[mi][ni][j] + bias[mb + j];
                    pk[j] = f2bf(fmaxf(v, 0.f));
                }
                *(ushort4*)((unsigned short*)out + (size_t)n * M + mb) =
                    make_ushort4(pk[0], pk[1], pk[2], pk[3]);
            }
        }
    } else {
        float part[2] = {0.f, 0.f};
        #pragma unroll
        for (int mi = 0; mi < 4; ++mi) {
            #pragma unroll
            for (int ni = 0; ni < 2; ++ni) {
                int mb = wr * 64 + mi * 16 + (lane >> 4) * 4;   // m0 == 0 for EPI=0
                int n  = n0 + wc * 32 + ni * 16 + (lane & 15);
                bool nok = (n < Nreal);
                int b = n / T, t = n - b * T;
                #pragma unroll
                for (int j = 0; j < 4; ++j) {
                    int m = mb + j;
                    if (m < NATT) {
                        float v = acc[mi][ni][j] + bias[m];
                        part[ni] += v * v;
                        if (nok)
                            ((float*)out)[((size_t)(b * NATT + m)) * T + t] = v;
                    }
                }
            }
        }
        if (SSQ) {
            #pragma unroll
            for (int ni = 0; ni < 2; ++ni) {
                part[ni] += __shfl_xor(part[ni], 16);
                part[ni] += __shfl_xor(part[ni], 32);
            }
            if ((lane >> 4) == 0) {
                red[wr * 64 + wc * 32 + (lane & 15)]      = part[0];
                red[wr * 64 + wc * 32 + 16 + (lane & 15)] = part[1];
            }
            __syncthreads();
            if (tid < 64) {
                int n = n0 + tid;
                if (n < Nreal) ssq[n] = red[tid] + red[64 + tid];
            }
        }
    }
}

// ---------------------------------------------------------------------------
// stage1: keys conv1 only (256 blocks)
__global__ __launch_bounds__(256)
void gemm_stage1(const unsigned short* __restrict__ Abf1, const unsigned short* __restrict__ Bt1,
                 const float* __restrict__ kb1, unsigned short* __restrict__ kc1bt) {
    __shared__ __attribute__((aligned(16))) unsigned short As[128 * 64];
    __shared__ __attribute__((aligned(16))) unsigned short Bs[64 * 64];
    int bx = blockIdx.x;
    int y = bx >> 5, x = bx & 31;
    gemm_dev<1, 0>(Abf1, Bt1, kb1, kc1bt, nullptr, 1024, 1536, 0, 0,
                   y * 128, x * 64, As, Bs, nullptr);
}

// ---------------------------------------------------------------------------
// stage2: keys conv2 + k2 (32 blocks) || fused query chain conv1->2->3 (+q2)
// Query chain per block: owns 64 t-columns (n0..n0+63 of 8000).
//   conv1 (M=256,K=256) from global Btq -> LDS B2 [64][256] bf16 (relu+bias)
//   conv2 (M=128,K=256) B from LDS B2  -> LDS B3 [64][128] bf16 (relu+bias)
//   conv3 (M=128,K=128) B from LDS B3  -> qenc f32 + q2 (SSQ)
// LDS writes/reads share the 16B-group XOR swizzle: byteoff ^ ((row&7)<<4).
__global__ __launch_bounds__(256)
void gemm_stage2(const unsigned short* __restrict__ Abf2, const unsigned short* __restrict__ kc1bt,
                 const float* __restrict__ kb2, float* __restrict__ kenc, float* __restrict__ k2,
                 const unsigned short* __restrict__ A1q, const unsigned short* __restrict__ Btq,
                 const float* __restrict__ pqb1,
                 const unsigned short* __restrict__ A2q, const float* __restrict__ pqb2,
                 const unsigned short* __restrict__ A3q, const float* __restrict__ qb3,
                 float* __restrict__ qenc, float* __restrict__ q2) {
    __shared__ __attribute__((aligned(16))) unsigned short As[128 * 64];   // 16KB
    __shared__ __attribute__((aligned(16))) unsigned short Bs[64 * 64];    // 8KB
    __shared__ __attribute__((aligned(16))) unsigned short B2[64 * 256];   // 32KB
    __shared__ __attribute__((aligned(16))) unsigned short B3[64 * 128];   // 16KB
    __shared__ float red[128];
    int bx = blockIdx.x;
    if (bx < 32) {
        gemm_dev<0, 1>(Abf2, kc1bt, kb2, kenc, k2, 128, 1024, NT2, 2048,
                       0, bx * 64, As, Bs, red);
        return;
    }
    // ---- fused query chain ----
    int n0 = (bx - 32) * 64;
    int tid = threadIdx.x, lane = tid & 63, wv = tid >> 6;
    int wr = wv >> 1, wc = wv & 1;
    int srow = lane >> 3;
    int selem = (((lane & 7) * 16) ^ ((srow & 7) << 4)) >> 1;

    // phase 1: conv1 (M=256 via 2 m-chunks, K=256), B from global Btq
    #pragma unroll
    for (int mc = 0; mc < 2; ++mc) {
        int m0 = mc * 128;
        f32x4 acc[4][2] = {};
        for (int k0 = 0; k0 < 256; k0 += 64) {
            #pragma unroll
            for (int i = 0; i < 4; ++i) {
                int ch = wv * 4 + i;
                gload_lds16(A1q + (size_t)(m0 + ch * 8 + srow) * 256 + k0 + selem, (char*)As + ch * 1024);
            }
            #pragma unroll
            for (int i = 0; i < 2; ++i) {
                int ch = wv * 2 + i;
                gload_lds16(Btq + (size_t)(n0 + ch * 8 + srow) * 256 + k0 + selem, (char*)Bs + ch * 1024);
            }
            __syncthreads();
            #pragma unroll
            for (int ks = 0; ks < 2; ++ks) {
                bf16x8 af[4], bfr[2];
                int kb = ks * 64 + (lane >> 4) * 16;
                #pragma unroll
                for (int mi = 0; mi < 4; ++mi) {
                    int row = wr * 64 + mi * 16 + (lane & 15);
                    af[mi] = *(const bf16x8*)((const char*)As + row * 128 + (kb ^ ((row & 7) << 4)));
                }
                #pragma unroll
                for (int ni = 0; ni < 2; ++ni) {
                    int row = wc * 32 + ni * 16 + (lane & 15);
                    bfr[ni] = *(const bf16x8*)((const char*)Bs + row * 128 + (kb ^ ((row & 7) << 4)));
                }
                #pragma unroll
                for (int mi = 0; mi < 4; ++mi)
                    #pragma unroll
                    for (int ni = 0; ni < 2; ++ni)
                        acc[mi][ni] = __builtin_amdgcn_mfma_f32_16x16x32_bf16(af[mi], bfr[ni], acc[mi][ni], 0, 0, 0);
            }
            __syncthreads();
        }
        // epilogue -> LDS B2[row][m], row stride 512B, swizzled
        #pragma unroll
        for (int mi = 0; mi < 4; ++mi) {
            #pragma unroll
            for (int ni = 0; ni < 2; ++ni) {
                int mb = m0 + wr * 64 + mi * 16 + (lane >> 4) * 4;
                int row = wc * 32 + ni * 16 + (lane & 15);
                unsigned short pk[4];
                #pragma unroll
                for (int j = 0; j < 4; ++j) {
                    float v = acc[mi][ni][j] + pqb1[mb + j];
                    pk[j] = f2bf(fmaxf(v, 0.f));
                }
                int bo = mb * 2;
                int addr = row * 512 + ((bo & ~15) ^ ((row & 7) << 4)) + (bo & 15);
                *(ushort4*)((char*)B2 + addr) = make_ushort4(pk[0], pk[1], pk[2], pk[3]);
            }
        }
    }
    // phase 2: conv2 (M=128, K=256), B resident in LDS B2
    {
        f32x4 acc[4][2] = {};
        for (int k0 = 0; k0 < 256; k0 += 64) {
            #pragma unroll
            for (int i = 0; i < 4; ++i) {
                int ch = wv * 4 + i;
                gload_lds16(A2q + (size_t)(ch * 8 + srow) * 256 + k0 + selem, (char*)As + ch * 1024);
            }
            __syncthreads();   // As ready AND (first iter) B2 writes complete
            #pragma unroll
            for (int ks = 0; ks < 2; ++ks) {
                bf16x8 af[4], bfr[2];
                int kb = ks * 64 + (lane >> 4) * 16;
                #pragma unroll
                for (int mi = 0; mi < 4; ++mi) {
                    int row = wr * 64 + mi * 16 + (lane & 15);
                    af[mi] = *(const bf16x8*)((const char*)As + row * 128 + (kb ^ ((row & 7) << 4)));
                }
                #pragma unroll
                for (int ni = 0; ni < 2; ++ni) {
                    int row = wc * 32 + ni * 16 + (lane & 15);
                    int kbyte = k0 * 2 + kb;
                    bfr[ni] = *(const bf16x8*)((const char*)B2 + row * 512 + (kbyte ^ ((row & 7) << 4)));
                }
                #pragma unroll
                for (int mi = 0; mi < 4; ++mi)
                    #pragma unroll
                    for (int ni = 0; ni < 2; ++ni)
                        acc[mi][ni] = __builtin_amdgcn_mfma_f32_16x16x32_bf16(af[mi], bfr[ni], acc[mi][ni], 0, 0, 0);
            }
            __syncthreads();
        }
        // epilogue -> LDS B3[row][m], row stride 256B, swizzled
        #pragma unroll
        for (int mi = 0; mi < 4; ++mi) {
            #pragma unroll
            for (int ni = 0; ni < 2; ++ni) {
                int mb = wr * 64 + mi * 16 + (lane >> 4) * 4;
                int row = wc * 32 + ni * 16 + (lane & 15);
                unsigned short pk[4];
                #pragma unroll
                for (int j = 0; j < 4; ++j) {
                    float v = acc[mi][ni][j] + pqb2[mb + j];
                    pk[j] = f2bf(fmaxf(v, 0.f));
                }
                int bo = mb * 2;
                int addr = row * 256 + ((bo & ~15) ^ ((row & 7) << 4)) + (bo & 15);
                *(ushort4*)((char*)B3 + addr) = make_ushort4(pk[0], pk[1], pk[2], pk[3]);
            }
        }
    }
    // phase 3: conv3 (M=128, K=128), B resident in LDS B3
    {
        f32x4 acc[4][2] = {};
        for (int k0 = 0; k0 < 128; k0 += 64) {
            #pragma unroll
            for (int i = 0; i < 4; ++i) {
                int ch = wv * 4 + i;
                gload_lds16(A3q + (size_t)(ch * 8 + srow) * 128 + k0 + selem, (char*)As + ch * 1024);
            }
            __syncthreads();   // As ready AND (first iter) B3 writes complete
            #pragma unroll
            for (int ks = 0; ks < 2; ++ks) {
                bf16x8 af[4], bfr[2];
                int kb = ks * 64 + (lane >> 4) * 16;
                #pragma unroll
                for (int mi = 0; mi < 4; ++mi) {
                    int row = wr * 64 + mi * 16 + (lane & 15);
                    af[mi] = *(const bf16x8*)((const char*)As + row * 128 + (kb ^ ((row & 7) << 4)));
                }
                #pragma unroll
                for (int ni = 0; ni < 2; ++ni) {
                    int row = wc * 32 + ni * 16 + (lane & 15);
                    int kbyte = k0 * 2 + kb;
                    bfr[ni] = *(const bf16x8*)((const char*)B3 + row * 256 + (kbyte ^ ((row & 7) << 4)));
                }
                #pragma unroll
                for (int mi = 0; mi < 4; ++mi)
                    #pragma unroll
                    for (int ni = 0; ni < 2; ++ni)
                        acc[mi][ni] = __builtin_amdgcn_mfma_f32_16x16x32_bf16(af[mi], bfr[ni], acc[mi][ni], 0, 0, 0);
            }
            __syncthreads();
        }
        // epilogue: qenc f32 + q2 (SSQ), n = n0+.. in [0,8000)
        float part[2] = {0.f, 0.f};
        #pragma unroll
        for (int mi = 0; mi < 4; ++mi) {
            #pragma unroll
            for (int ni = 0; ni < 2; ++ni) {
                int mb = wr * 64 + mi * 16 + (lane >> 4) * 4;
                int n  = n0 + wc * 32 + ni * 16 + (lane & 15);
                int b = n / NT1, t = n - b * NT1;
                #pragma unroll
                for (int j = 0; j < 4; ++j) {
                    int m = mb + j;
                    if (m < NATT) {
                        float v = acc[mi][ni][j] + qb3[m];
                        part[ni] += v * v;
                        qenc[((size_t)(b * NATT + m)) * NT1 + t] = v;
                    }
                }
            }
        }
        #pragma unroll
        for (int ni = 0; ni < 2; ++ni) {
            part[ni] += __shfl_xor(part[ni], 16);
            part[ni] += __shfl_xor(part[ni], 32);
        }
        if ((lane >> 4) == 0) {
            red[wr * 64 + wc * 32 + (lane & 15)]      = part[0];
            red[wr * 64 + wc * 32 + 16 + (lane & 15)] = part[1];
        }
        __syncthreads();
        if (tid < 64) q2[n0 + tid] = red[tid] + red[64 + tid];
    }
}

// ---------------------------------------------------------------------------
// attn: fused QK^T + dist + log_softmax + log prior + masked softmax.
__global__ void attn_kernel(const float* __restrict__ qenc, const float* __restrict__ kenc,
                            const float* __restrict__ q2, const float* __restrict__ k2,
                            const float* __restrict__ prior, const int* __restrict__ lens,
                            float* __restrict__ out_attn, float* __restrict__ out_lp) {
    __shared__ float kl[16][256];
    __shared__ float ql[16][32];
    int b = blockIdx.y;
    int t0 = blockIdx.x * 32;
    int tid = threadIdx.x;
    int lane = tid & 63;
    int wv = tid >> 6;
    int s0 = lane * 4;
    float acc[8][4] = {};
    for (int ci0 = 0; ci0 < NATT; ci0 += 16) {
        for (int i = tid; i < 16 * 256; i += 256) {
            int ci = i >> 8, s = i & 255;
            kl[ci][s] = kenc[((size_t)(b * NATT + ci0 + ci)) * NT2 + s];
        }
        for (int i = tid; i < 16 * 32; i += 256) {
            int ci = i >> 5, tt = i & 31;
            int tg = t0 + tt;
            ql[ci][tt] = (tg < NT1) ? qenc[((size_t)(b * NATT + ci0 + ci)) * NT1 + tg] : 0.f;
        }
        __syncthreads();
        #pragma unroll
        for (int ci = 0; ci < 16; ++ci) {
            float kv[4];
            #pragma unroll
            for (int j = 0; j < 4; ++j) kv[j] = kl[ci][s0 + j];
            #pragma unroll
            for (int r = 0; r < 8; ++r) {
                float qv = ql[ci][wv * 8 + r];
                #pragma unroll
                for (int j = 0; j < 4; ++j) acc[r][j] += qv * kv[j];
            }
        }
        __syncthreads();
    }
    int len = lens[b];
    float k2v[4];
    #pragma unroll
    for (int j = 0; j < 4; ++j) k2v[j] = k2[b * NT2 + s0 + j];
    #pragma unroll
    for (int r = 0; r < 8; ++r) {
        int t = t0 + wv * 8 + r;
        if (t >= NT1) continue;
        float q2v = q2[b * NT1 + t];
        float lg[4];
        float mx = -INFINITY;
        #pragma unroll
        for (int j = 0; j < 4; ++j) {
            lg[j] = -FTEMP * (q2v + k2v[j] - 2.f * acc[r][j]);
            mx = fmaxf(mx, lg[j]);
        }
        for (int off = 32; off > 0; off >>= 1) mx = fmaxf(mx, __shfl_xor(mx, off));
        float se = 0.f;
        #pragma unroll
        for (int j = 0; j < 4; ++j) se += __expf(lg[j] - mx);
        for (int off = 32; off > 0; off >>= 1) se += __shfl_xor(se, off);
        float logZ = mx + __logf(se);
        const float* pr = &prior[((size_t)b * NT1 + t) * NT2 + s0];
        float lp[4];
        float mx2 = -INFINITY;
        #pragma unroll
        for (int j = 0; j < 4; ++j) {
            lp[j] = lg[j] - logZ + __logf(pr[j] + 1e-8f);
            if (s0 + j < len) mx2 = fmaxf(mx2, lp[j]);
        }
        for (int off = 32; off > 0; off >>= 1) mx2 = fmaxf(mx2, __shfl_xor(mx2, off));
        float se2 = 0.f;
        float ex[4];
        #pragma unroll
        for (int j = 0; j < 4; ++j) {
            ex[j] = (s0 + j < len) ? __expf(lp[j] - mx2) : 0.f;
            se2 += ex[j];
        }
        for (int off = 32; off > 0; off >>= 1) se2 += __shfl_xor(se2, off);
        float inv = 1.f / se2;
        size_t o = ((size_t)b * NT1 + t) * NT2 + s0;
        #pragma unroll
        for (int j = 0; j < 4; ++j) {
            out_attn[o + j] = ex[j] * inv;
            out_lp[o + j]   = lp[j];
        }
    }
}

// ---------------------------------------------------------------------------
extern "C" void kernel_launch(void* const* d_in, const int* in_sizes, int n_in,
                              void* d_out, int out_size, void* d_ws, size_t ws_size,
                              hipStream_t stream) {
    (void)in_sizes; (void)n_in; (void)out_size; (void)ws_size;
    const float* queries = (const float*)d_in[0];
    const float* keys    = (const float*)d_in[1];
    const float* prior   = (const float*)d_in[2];
    const float* spk     = (const float*)d_in[3];
    const float* emo     = (const float*)d_in[4];
    const float* kw1     = (const float*)d_in[5];
    const float* kb1     = (const float*)d_in[6];
    const float* kw2     = (const float*)d_in[7];
    const float* kb2     = (const float*)d_in[8];
    const float* qw1     = (const float*)d_in[9];
    const float* qb1     = (const float*)d_in[10];
    const float* qw2     = (const float*)d_in[11];
    const float* qb2     = (const float*)d_in[12];
    const float* qw3     = (const float*)d_in[13];
    const float* qb3     = (const float*)d_in[14];
    const float* spk_kw  = (const float*)d_in[15];
    const float* spk_kb  = (const float*)d_in[16];
    const float* spk_qw  = (const float*)d_in[17];
    const float* spk_qb  = (const float*)d_in[18];
    const float* emo_kw  = (const float*)d_in[19];
    const float* emo_kb  = (const float*)d_in[20];
    const float* emo_qw  = (const float*)d_in[21];
    const float* emo_qb  = (const float*)d_in[22];
    const void*  mask    = d_in[23];

    float* w = (float*)d_ws;
    size_t off = 0;
    float* shiftK = w + off; off += NB * NTXT;
    float* shiftQ = w + off; off += NB * NMEL;
    int*   lens   = (int*)(w + off); off += 16;
    float* k2     = w + off; off += NB * NT2;
    float* q2     = w + off; off += NB * NT1;
    float* kenc   = w + off; off += (size_t)NB * NATT * NT2;
    float* qenc   = w + off; off += (size_t)NB * NATT * NT1;
    unsigned short* Bt1   = (unsigned short*)(w + off); off += (size_t)2048 * 1536 / 2;
    unsigned short* kc1bt = (unsigned short*)(w + off); off += (size_t)2048 * 1024 / 2;
    unsigned short* Btq   = (unsigned short*)(w + off); off += (size_t)8064 * 256 / 2;
    unsigned short* Abf1  = (unsigned short*)(w + off); off += (size_t)1024 * 1536 / 2;
    unsigned short* Abf2  = (unsigned short*)(w + off); off += (size_t)128 * 1024 / 2;
    unsigned short* A1q   = (unsigned short*)(w + off); off += (size_t)256 * 256 / 2;
    unsigned short* A2q   = (unsigned short*)(w + off); off += (size_t)128 * 256 / 2;
    unsigned short* A3q   = (unsigned short*)(w + off); off += (size_t)128 * 128 / 2;
    float* pqb1 = w + off; off += 256;
    float* pqb2 = w + off; off += 128;

    float* out_attn = (float*)d_out;
    float* out_lp   = out_attn + (size_t)NB * NT1 * NT2;

    // 1: all prep (lens + shifts + weight casts)
    prep_all<<<PW_BLOCKS + SH_BLOCKS + 1, 256, 0, stream>>>(
        kw1, kw2, qw1, qw2, qw3, qb1, qb2,
        Abf1, Abf2, A1q, A2q, A3q, pqb1, pqb2,
        spk, emo, spk_kw, spk_kb, emo_kw, emo_kb,
        spk_qw, spk_qb, emo_qw, emo_qb, shiftK, shiftQ,
        mask, lens);

    // 2: both im2cols
    im2col_all<<<384, 256, 0, stream>>>(keys, shiftK, Bt1, queries, shiftQ, Btq);

    // 3: keys conv1 (256 blocks)
    gemm_stage1<<<256, 256, 0, stream>>>(Abf1, Bt1, kb1, kc1bt);

    // 4: keys conv2 (+k2, 32 blocks) || fused query chain (+q2, 125 blocks)
    gemm_stage2<<<157, 256, 0, stream>>>(
        Abf2, kc1bt, kb2, kenc, k2,
        A1q, Btq, pqb1, A2q, pqb2, A3q, qb3, qenc, q2);

    // 5: fused attention
    attn_kernel<<<dim3((NT1 + 31) / 32, NB), 256, 0, stream>>>(
        qenc, kenc, q2, k2, prior, lens, out_attn, out_lp);
}